// Round 6
// baseline (101.572 us; speedup 1.0000x reference)
//
#include <hip/hip_runtime.h>
#include <cstdint>
#include <cstddef>

typedef __bf16 bf16x8 __attribute__((ext_vector_type(8)));
typedef unsigned short u16x8 __attribute__((ext_vector_type(8)));
typedef float f32x4 __attribute__((ext_vector_type(4)));
typedef unsigned u32x4 __attribute__((ext_vector_type(4)));

#define MFMA(a, b, c) __builtin_amdgcn_mfma_f32_16x16x32_bf16(a, b, c, 0, 0, 0)
#define WAITV(N) asm volatile("s_waitcnt vmcnt(" #N ")" ::: "memory")
#define SBAR()   __builtin_amdgcn_sched_barrier(0)

__device__ __forceinline__ unsigned short f2bfbits(float x) {
    unsigned u = __builtin_bit_cast(unsigned, x);
    u += 0x7FFFu + ((u >> 16) & 1u);           // round-to-nearest-even
    return (unsigned short)(u >> 16);
}

// HW packed f32->bf16 (RNE)
__device__ __forceinline__ unsigned cvt_pk(float lo, float hi) {
    unsigned r;
    asm("v_cvt_pk_bf16_f32 %0, %1, %2" : "=v"(r) : "v"(lo), "v"(hi));
    return r;
}

__device__ __forceinline__ bf16x8 pack8(f32x4 a, f32x4 b) {
    u32x4 t = { cvt_pk(a[0], a[1]), cvt_pk(a[2], a[3]),
                cvt_pk(b[0], b[1]), cvt_pk(b[2], b[3]) };
    return __builtin_bit_cast(bf16x8, t);
}

// async global->LDS DMA, 16B/lane; LDS dest = wave-uniform base + lane*16.
__device__ __forceinline__ void gl_lds16(const void* g, void* l) {
    __builtin_amdgcn_global_load_lds(
        (const __attribute__((address_space(1))) unsigned int*)g,
        (__attribute__((address_space(3))) unsigned int*)l, 16, 0, 0);
}

// ---------------------------------------------------------------------------
// Kernel 1: projections (unchanged; passed rounds 1-4).
// ---------------------------------------------------------------------------
__global__ __launch_bounds__(256) void proj_kernel(
    const float* __restrict__ q_data, const float* __restrict__ m_data,
    const float* __restrict__ Wq, const float* __restrict__ Wk,
    const float* __restrict__ Wv, const float* __restrict__ Wg,
    const float* __restrict__ bg,
    unsigned short* __restrict__ Qb, unsigned short* __restrict__ Kb,
    unsigned short* __restrict__ VT, float* __restrict__ gate)
{
    __shared__ unsigned short vt_lds[128][80];
    const int mat   = blockIdx.x >> 7;
    const int mtile = blockIdx.x & 127;
    const int wave  = threadIdx.x >> 6;
    const int lane  = threadIdx.x & 63;
    const int r16 = lane & 15, g = lane >> 4;
    const int rowbase = mtile * 64 + wave * 16;

    const float* src = (mat == 1 || mat == 2) ? m_data : q_data;
    const float* W   = (mat == 0) ? Wq : (mat == 1) ? Wk : (mat == 2) ? Wv : Wg;

    bf16x8 afrag[4];
    {
        const float* arow = src + (size_t)(rowbase + r16) * 128;
        #pragma unroll
        for (int kk = 0; kk < 4; ++kk) {
            f32x4 lo = *(const f32x4*)(arow + kk * 32 + g * 8);
            f32x4 hi = *(const f32x4*)(arow + kk * 32 + g * 8 + 4);
            afrag[kk] = pack8(lo, hi);
        }
    }

    f32x4 acc[8];
    #pragma unroll
    for (int n0 = 0; n0 < 8; ++n0) {
        f32x4 a = {0.f, 0.f, 0.f, 0.f};
        #pragma unroll
        for (int kk = 0; kk < 4; ++kk) {
            f32x4 lo, hi;
            #pragma unroll
            for (int i = 0; i < 4; ++i) {
                lo[i] = W[(size_t)(kk * 32 + g * 8 + i) * 128 + n0 * 16 + r16];
                hi[i] = W[(size_t)(kk * 32 + g * 8 + 4 + i) * 128 + n0 * 16 + r16];
            }
            a = MFMA(afrag[kk], pack8(lo, hi), a);
        }
        acc[n0] = a;
    }

    if (mat <= 1) {
        unsigned short* dst = (mat == 0) ? Qb : Kb;
        #pragma unroll
        for (int n0 = 0; n0 < 8; ++n0) {
            int n = n0 * 16 + r16, h = n >> 5, d = n & 31;
            #pragma unroll
            for (int i = 0; i < 4; ++i) {
                int grow = rowbase + 4 * g + i;
                int bb = grow >> 11, ns = grow & 2047;
                dst[(size_t)(bb * 4 + h) * 65536 + (size_t)ns * 32 + d] =
                    f2bfbits(acc[n0][i]);
            }
        }
    } else if (mat == 2) {
        #pragma unroll
        for (int n0 = 0; n0 < 8; ++n0) {
            int n = n0 * 16 + r16;
            #pragma unroll
            for (int i = 0; i < 4; ++i)
                vt_lds[n][wave * 16 + 4 * g + i] = f2bfbits(acc[n0][i]);
        }
        __syncthreads();
        int bb = rowbase >> 11;
        int nsbase = (mtile * 64) & 2047;
        #pragma unroll
        for (int it = 0; it < 4; ++it) {
            int idx = (threadIdx.x + it * 256) * 8;
            int n = idx >> 6, mm = idx & 63;
            u16x8 v = *(const u16x8*)&vt_lds[n][mm];
            *(u16x8*)(VT + (size_t)(bb * 128 + n) * 2048 + nsbase + mm) = v;
        }
    } else {
        #pragma unroll
        for (int n0 = 0; n0 < 8; ++n0) {
            int n = n0 * 16 + r16;
            float bgv = bg[n];
            #pragma unroll
            for (int i = 0; i < 4; ++i) {
                int grow = rowbase + 4 * g + i;
                float x = acc[n0][i] + bgv;
                gate[(size_t)grow * 128 + n] = 1.0f / (1.0f + __expf(-x));
            }
        }
    }
}

// ---------------------------------------------------------------------------
// Kernel 2: flash attention + gate -> bf16 wa workspace.
// 1024 blocks = (b, q-tile, head-pair) x 128 threads (2 waves = 2 heads).
// Each wave runs a fully PRIVATE pipeline: ring-4 LDS buffers (8KB each:
// bias 2K + nbias 2K + K 2K sigma-permuted + V 2K), all filled by
// global_load_lds DMA, depth-3 prefetch, per-wave counted vmcnt (never
// drains mid-loop), ZERO barriers in the loop. XOR swizzles applied
// both-sides (pre-swizzled global source / swizzled LDS read).
// ---------------------------------------------------------------------------
__global__ __launch_bounds__(128) void attn_kernel(
    const unsigned short* __restrict__ Qb, const unsigned short* __restrict__ Kb,
    const unsigned short* __restrict__ VT, const float* __restrict__ gate,
    const float* __restrict__ bias, const float* __restrict__ nbias,
    unsigned short* __restrict__ WA)
{
    __shared__ char ldsbuf[2][4][8192];          // 64 KB: [wave][ring][buffer]

    const int hp = blockIdx.x & 1;
    const int qt = (blockIdx.x >> 1) & 127;
    const int b  = blockIdx.x >> 8;
    const int qb = qt * 16;
    const int w    = threadIdx.x >> 6;
    const int h    = hp * 2 + w;
    const int lane = threadIdx.x & 63;
    const int q16 = lane & 15, g = lane >> 4;

    const size_t bh = (size_t)(b * 4 + h);
    const unsigned short* Kp = Kb + bh * 65536;
    const unsigned short* Vp = VT + bh * 65536;
    const float* bias_b = bias  + ((size_t)b * 2048 + qb) * 2048;
    const float* nb_h   = nbias + ((size_t)h * 2048 + qb) * 2048;

    bf16x8 qfrag = *(const bf16x8*)(Qb + bh * 65536 + (size_t)(qb + q16) * 32 + g * 8);

    // staging lane decompositions
    const int ls8 = lane >> 3, lc8 = lane & 7;        // bias/nbias chunks
    const int rho = lane >> 2, l4 = lane & 3;         // K/V chunks
    const int krow_l = ((rho >> 2) << 3) + (rho & 3); // sigma permutation
    const int kvsw = l4 ^ (rho & 3);                  // K/V source swizzle

    float m = -1e30f, lsum = 0.f;
    f32x4 acc0 = {0, 0, 0, 0}, acc1 = {0, 0, 0, 0};

    auto issue = [&](int it, int bf) {
        const int kb = it * 32;
        char* base = &ldsbuf[w][bf][0];
        #pragma unroll
        for (int c = 0; c < 2; ++c) {
            int row = 8 * c + ls8;
            int csw = (lc8 * 4) ^ ((row & 7) << 2);
            gl_lds16(bias_b + (size_t)row * 2048 + kb + csw, base + c * 1024);
            gl_lds16(nb_h   + (size_t)row * 2048 + kb + csw, base + 2048 + c * 1024);
        }
        #pragma unroll
        for (int t = 0; t < 2; ++t)
            gl_lds16(Kp + (size_t)(kb + 4 * t + krow_l) * 32 + kvsw * 8,
                     base + 4096 + t * 1024);
        #pragma unroll
        for (int j = 0; j < 2; ++j)
            gl_lds16(Vp + (size_t)(16 * j + rho) * 2048 + kb + kvsw * 8,
                     base + 6144 + j * 1024);
    };

    auto step = [&](int bf) {
        const char* buf = &ldsbuf[w][bf][0];
        const int bsw = (q16 & 7) << 4;
        const int ksw = (g * 16) ^ ((q16 & 3) << 4);
        f32x4 bb0 = *(const f32x4*)(buf + q16 * 128 + ((g * 32) ^ bsw));
        f32x4 bb1 = *(const f32x4*)(buf + q16 * 128 + ((16 + g * 32) ^ bsw));
        f32x4 nn0 = *(const f32x4*)(buf + 2048 + q16 * 128 + ((g * 32) ^ bsw));
        f32x4 nn1 = *(const f32x4*)(buf + 2048 + q16 * 128 + ((16 + g * 32) ^ bsw));
        bf16x8 kf0 = *(const bf16x8*)(buf + 4096 + q16 * 64 + ksw);
        bf16x8 kf1 = *(const bf16x8*)(buf + 5120 + q16 * 64 + ksw);
        bf16x8 vf0 = *(const bf16x8*)(buf + 6144 + q16 * 64 + ksw);
        bf16x8 vf1 = *(const bf16x8*)(buf + 7168 + q16 * 64 + ksw);

        f32x4 z = {0, 0, 0, 0};
        f32x4 s0 = MFMA(kf0, qfrag, z);          // s0[i] = S[kb+8g+i][q16]
        f32x4 s1 = MFMA(kf1, qfrag, z);          // s1[i] = S[kb+4+8g+i][q16]
        s0 += bb0 + nn0;
        s1 += bb1 + nn1;

        float mx = fmaxf(fmaxf(fmaxf(s0[0], s0[1]), fmaxf(s0[2], s0[3])),
                         fmaxf(fmaxf(s1[0], s1[1]), fmaxf(s1[2], s1[3])));
        mx = fmaxf(mx, __shfl_xor(mx, 16));
        mx = fmaxf(mx, __shfl_xor(mx, 32));
        float m_new = fmaxf(m, mx);
        float alpha = __expf(m - m_new);
        float ps = 0.f;
        #pragma unroll
        for (int i = 0; i < 4; ++i) { s0[i] = __expf(s0[i] - m_new); ps += s0[i]; }
        #pragma unroll
        for (int i = 0; i < 4; ++i) { s1[i] = __expf(s1[i] - m_new); ps += s1[i]; }
        ps += __shfl_xor(ps, 16);
        ps += __shfl_xor(ps, 32);
        lsum = lsum * alpha + ps;
        m = m_new;

        u32x4 pc = { cvt_pk(s0[0], s0[1]), cvt_pk(s0[2], s0[3]),
                     cvt_pk(s1[0], s1[1]), cvt_pk(s1[2], s1[3]) };
        bf16x8 p = __builtin_bit_cast(bf16x8, pc);

        acc0 *= alpha;
        acc1 *= alpha;
        acc0 = MFMA(vf0, p, acc0);               // lane: out[q16][d=4g+i]
        acc1 = MFMA(vf1, p, acc1);               // lane: out[q16][d=16+4g+i]
    };

    issue(0, 0);
    issue(1, 1);
    issue(2, 2);

    #pragma unroll 1
    for (int it = 0; it < 60; it += 4) {
        WAITV(16); SBAR(); issue(it + 3, (it + 3) & 3); step(it & 3);
        WAITV(16); SBAR(); issue(it + 4, (it + 4) & 3); step((it + 1) & 3);
        WAITV(16); SBAR(); issue(it + 5, (it + 5) & 3); step((it + 2) & 3);
        WAITV(16); SBAR(); issue(it + 6, (it + 6) & 3); step((it + 3) & 3);
    }
    WAITV(16); SBAR(); issue(63, 3); step(0);    // it = 60
    WAITV(16); SBAR(); step(1);                  // it = 61
    WAITV(8);  SBAR(); step(2);                  // it = 62
    WAITV(0);  SBAR(); step(3);                  // it = 63

    // ---- epilogue: /l, gate (lane-local), write bf16 wa to workspace ----
    float invL = 1.0f / lsum;
    const float* grow = gate + ((size_t)b * 2048 + qb + q16) * 128 + h * 32;
    f32x4 g0 = *(const f32x4*)(grow + 4 * g);
    f32x4 g1 = *(const f32x4*)(grow + 16 + 4 * g);
    uint2 t0, t1;
    t0.x = cvt_pk(acc0[0] * invL * g0[0], acc0[1] * invL * g0[1]);
    t0.y = cvt_pk(acc0[2] * invL * g0[2], acc0[3] * invL * g0[3]);
    t1.x = cvt_pk(acc1[0] * invL * g1[0], acc1[1] * invL * g1[1]);
    t1.y = cvt_pk(acc1[2] * invL * g1[2], acc1[3] * invL * g1[3]);
    unsigned short* wrow = WA + ((size_t)b * 2048 + qb + q16) * 128 + h * 32;
    *(uint2*)(wrow + 4 * g)      = t0;
    *(uint2*)(wrow + 16 + 4 * g) = t1;
}

// ---------------------------------------------------------------------------
// Kernel 3: out = wa @ Wo + bo.  128 blocks x 256 threads, proj-style.
// ---------------------------------------------------------------------------
__global__ __launch_bounds__(256) void outproj_kernel(
    const unsigned short* __restrict__ WA, const float* __restrict__ Wo,
    const float* __restrict__ bo, float* __restrict__ out)
{
    const int mtile = blockIdx.x;
    const int wave = threadIdx.x >> 6;
    const int lane = threadIdx.x & 63;
    const int r16 = lane & 15, g = lane >> 4;
    const int rowbase = mtile * 64 + wave * 16;

    bf16x8 afrag[4];
    #pragma unroll
    for (int kk = 0; kk < 4; ++kk)
        afrag[kk] = *(const bf16x8*)(WA + (size_t)(rowbase + r16) * 128 + kk * 32 + g * 8);

    #pragma unroll
    for (int n0 = 0; n0 < 8; ++n0) {
        f32x4 a = {0.f, 0.f, 0.f, 0.f};
        #pragma unroll
        for (int kk = 0; kk < 4; ++kk) {
            f32x4 lo, hi;
            #pragma unroll
            for (int i = 0; i < 4; ++i) {
                int k0 = kk * 32 + g * 8 + i;
                lo[i] = Wo[(size_t)k0 * 128 + n0 * 16 + r16];
                hi[i] = Wo[(size_t)(k0 + 4) * 128 + n0 * 16 + r16];
            }
            a = MFMA(afrag[kk], pack8(lo, hi), a);
        }
        float bov = bo[n0 * 16 + r16];
        #pragma unroll
        for (int i = 0; i < 4; ++i)
            out[(size_t)(rowbase + 4 * g + i) * 128 + n0 * 16 + r16] = a[i] + bov;
    }
}

// ---------------------------------------------------------------------------
extern "C" void kernel_launch(void* const* d_in, const int* in_sizes, int n_in,
                              void* d_out, int out_size, void* d_ws, size_t ws_size,
                              hipStream_t stream)
{
    const float* q_data = (const float*)d_in[0];
    const float* m_data = (const float*)d_in[1];
    const float* bias   = (const float*)d_in[2];
    const float* nbias  = (const float*)d_in[3];
    const float* Wq     = (const float*)d_in[4];
    const float* Wk     = (const float*)d_in[5];
    const float* Wv     = (const float*)d_in[6];
    const float* Wg     = (const float*)d_in[7];
    const float* bg     = (const float*)d_in[8];
    const float* Wo     = (const float*)d_in[9];
    const float* bo     = (const float*)d_in[10];
    float* out = (float*)d_out;

    unsigned short* Qb = (unsigned short*)d_ws;          // 2MB
    unsigned short* Kb = Qb + (1 << 20);                 // 2MB
    unsigned short* VT = Kb + (1 << 20);                 // 2MB
    float* gate = (float*)(VT + (1 << 20));              // 4MB
    unsigned short* WA = (unsigned short*)(gate + (1 << 20)); // 2MB

    proj_kernel<<<dim3(512), dim3(256), 0, stream>>>(
        q_data, m_data, Wq, Wk, Wv, Wg, bg, Qb, Kb, VT, gate);
    attn_kernel<<<dim3(1024), dim3(128), 0, stream>>>(
        Qb, Kb, VT, gate, bias, nbias, WA);
    outproj_kernel<<<dim3(128), dim3(256), 0, stream>>>(
        WA, Wo, bo, out);
}

// Round 9
// 91.272 us; speedup vs baseline: 1.1128x; 1.1128x over previous
//
#include <hip/hip_runtime.h>
#include <cstdint>
#include <cstddef>

typedef __bf16 bf16x8 __attribute__((ext_vector_type(8)));
typedef unsigned short u16x8 __attribute__((ext_vector_type(8)));
typedef float f32x4 __attribute__((ext_vector_type(4)));
typedef unsigned u32x4 __attribute__((ext_vector_type(4)));

#define MFMA(a, b, c) __builtin_amdgcn_mfma_f32_16x16x32_bf16(a, b, c, 0, 0, 0)

__device__ __forceinline__ unsigned short f2bfbits(float x) {
    unsigned u = __builtin_bit_cast(unsigned, x);
    u += 0x7FFFu + ((u >> 16) & 1u);           // round-to-nearest-even
    return (unsigned short)(u >> 16);
}

// HW packed f32->bf16 (RNE)
__device__ __forceinline__ unsigned cvt_pk(float lo, float hi) {
    unsigned r;
    asm("v_cvt_pk_bf16_f32 %0, %1, %2" : "=v"(r) : "v"(lo), "v"(hi));
    return r;
}

__device__ __forceinline__ bf16x8 pack8(f32x4 a, f32x4 b) {
    u32x4 t = { cvt_pk(a[0], a[1]), cvt_pk(a[2], a[3]),
                cvt_pk(b[0], b[1]), cvt_pk(b[2], b[3]) };
    return __builtin_bit_cast(bf16x8, t);
}

// async global->LDS DMA, 16B/lane; LDS dest = wave-uniform base + lane*16.
__device__ __forceinline__ void gl_lds16(const void* g, void* l) {
    __builtin_amdgcn_global_load_lds(
        (const __attribute__((address_space(1))) unsigned int*)g,
        (__attribute__((address_space(3))) unsigned int*)l, 16, 0, 0);
}

// ---------------------------------------------------------------------------
// Kernel 1: projections (unchanged; proven rounds 1-8).
// ---------------------------------------------------------------------------
__global__ __launch_bounds__(256) void proj_kernel(
    const float* __restrict__ q_data, const float* __restrict__ m_data,
    const float* __restrict__ Wq, const float* __restrict__ Wk,
    const float* __restrict__ Wv, const float* __restrict__ Wg,
    const float* __restrict__ bg,
    unsigned short* __restrict__ Qb, unsigned short* __restrict__ Kb,
    unsigned short* __restrict__ VT, float* __restrict__ gate)
{
    __shared__ unsigned short vt_lds[128][80];
    const int mat   = blockIdx.x >> 7;
    const int mtile = blockIdx.x & 127;
    const int wave  = threadIdx.x >> 6;
    const int lane  = threadIdx.x & 63;
    const int r16 = lane & 15, g = lane >> 4;
    const int rowbase = mtile * 64 + wave * 16;

    const float* src = (mat == 1 || mat == 2) ? m_data : q_data;
    const float* W   = (mat == 0) ? Wq : (mat == 1) ? Wk : (mat == 2) ? Wv : Wg;

    bf16x8 afrag[4];
    {
        const float* arow = src + (size_t)(rowbase + r16) * 128;
        #pragma unroll
        for (int kk = 0; kk < 4; ++kk) {
            f32x4 lo = *(const f32x4*)(arow + kk * 32 + g * 8);
            f32x4 hi = *(const f32x4*)(arow + kk * 32 + g * 8 + 4);
            afrag[kk] = pack8(lo, hi);
        }
    }

    f32x4 acc[8];
    #pragma unroll
    for (int n0 = 0; n0 < 8; ++n0) {
        f32x4 a = {0.f, 0.f, 0.f, 0.f};
        #pragma unroll
        for (int kk = 0; kk < 4; ++kk) {
            f32x4 lo, hi;
            #pragma unroll
            for (int i = 0; i < 4; ++i) {
                lo[i] = W[(size_t)(kk * 32 + g * 8 + i) * 128 + n0 * 16 + r16];
                hi[i] = W[(size_t)(kk * 32 + g * 8 + 4 + i) * 128 + n0 * 16 + r16];
            }
            a = MFMA(afrag[kk], pack8(lo, hi), a);
        }
        acc[n0] = a;
    }

    if (mat <= 1) {
        unsigned short* dst = (mat == 0) ? Qb : Kb;
        #pragma unroll
        for (int n0 = 0; n0 < 8; ++n0) {
            int n = n0 * 16 + r16, h = n >> 5, d = n & 31;
            #pragma unroll
            for (int i = 0; i < 4; ++i) {
                int grow = rowbase + 4 * g + i;
                int bb = grow >> 11, ns = grow & 2047;
                dst[(size_t)(bb * 4 + h) * 65536 + (size_t)ns * 32 + d] =
                    f2bfbits(acc[n0][i]);
            }
        }
    } else if (mat == 2) {
        #pragma unroll
        for (int n0 = 0; n0 < 8; ++n0) {
            int n = n0 * 16 + r16;
            #pragma unroll
            for (int i = 0; i < 4; ++i)
                vt_lds[n][wave * 16 + 4 * g + i] = f2bfbits(acc[n0][i]);
        }
        __syncthreads();
        int bb = rowbase >> 11;
        int nsbase = (mtile * 64) & 2047;
        #pragma unroll
        for (int it = 0; it < 4; ++it) {
            int idx = (threadIdx.x + it * 256) * 8;
            int n = idx >> 6, mm = idx & 63;
            u16x8 v = *(const u16x8*)&vt_lds[n][mm];
            *(u16x8*)(VT + (size_t)(bb * 128 + n) * 2048 + nsbase + mm) = v;
        }
    } else {
        #pragma unroll
        for (int n0 = 0; n0 < 8; ++n0) {
            int n = n0 * 16 + r16;
            float bgv = bg[n];
            #pragma unroll
            for (int i = 0; i < 4; ++i) {
                int grow = rowbase + 4 * g + i;
                float x = acc[n0][i] + bgv;
                gate[(size_t)grow * 128 + n] = 1.0f / (1.0f + __expf(-x));
            }
        }
    }
}

// ---------------------------------------------------------------------------
// Kernel 2: flash attention partials.  r4's PROVEN loop, verbatim, with the
// only changes being: (a) kv-split across 4 blocks (grid 2048 = split*512 +
// b*128 + qt, 16 iters each), (b) epilogue writes UNNORMALIZED partials
// (m, l, acc) to workspace instead of the fused wa/Wo epilogue, (c) wa_lds
// dropped -> 52KB LDS -> 3 blocks/CU.
// ---------------------------------------------------------------------------
__global__ __launch_bounds__(256, 2) void attn_kernel(
    const unsigned short* __restrict__ Qb, const unsigned short* __restrict__ Kb,
    const unsigned short* __restrict__ VT,
    const float* __restrict__ bias, const float* __restrict__ nbias,
    float* __restrict__ Pm, float* __restrict__ Pl, float* __restrict__ Pacc)
{
    __shared__ float biasT[2][16][32];               // 4KB
    __shared__ float nbT[2][4][16][32];              // 16KB
    __shared__ unsigned short kT[2][4][2][16][32];   // 16KB
    __shared__ unsigned short vT[2][4][32][32];      // 16KB

    const int split = blockIdx.x >> 9;
    const int rem   = blockIdx.x & 511;
    const int b  = rem >> 7;
    const int qb = (rem & 127) * 16;
    const int kv0 = split * 512;
    const int h    = threadIdx.x >> 6;
    const int lane = threadIdx.x & 63;
    const int q16 = lane & 15, g = lane >> 4;

    const size_t bh = (size_t)(b * 4 + h);
    const unsigned short* Kp = Kb + bh * 65536;
    const unsigned short* Vp = VT + bh * 65536;
    const float* bias_b = bias  + ((size_t)b * 2048 + qb) * 2048;
    const float* nb_h   = nbias + ((size_t)h * 2048 + qb) * 2048;

    bf16x8 qfrag = *(const bf16x8*)(Qb + bh * 65536 + (size_t)(qb + q16) * 32 + g * 8);

    // staging lane decompositions (r4 verbatim)
    const int ls8 = lane >> 3, lc8 = lane & 7;       // bias/nbias chunks
    const int rho = lane >> 2, l4 = lane & 3;        // K/V chunks
    const int krow_l = ((rho >> 2) << 3) + (rho & 3);   // sigma permutation

    float m = -1e30f, lsum = 0.f;
    f32x4 acc0 = {0, 0, 0, 0}, acc1 = {0, 0, 0, 0};

    auto stage = [&](int it) {
        if (it >= 16) return;
        const int bf = it & 1;
        const int kb = kv0 + it * 32;
        // nbias: 2 chunks (rows 8c+ls8), swizzled source
        #pragma unroll
        for (int c = 0; c < 2; ++c) {
            int row = 8 * c + ls8;
            int coldw = (lc8 * 4) ^ ((row & 7) << 2);
            gl_lds16(nb_h + (size_t)row * 2048 + kb + coldw,
                     (char*)&nbT[bf][h][0][0] + c * 1024);
        }
        // bias: 2 chunks staged by waves 0,1
        if (h < 2) {
            int row = 8 * h + ls8;
            int coldw = (lc8 * 4) ^ ((row & 7) << 2);
            gl_lds16(bias_b + (size_t)row * 2048 + kb + coldw,
                     (char*)&biasT[bf][0][0] + h * 1024);
        }
        // K: 2 chunks, sigma-permuted rows (slot rho holds row kb+4t+krow(rho))
        #pragma unroll
        for (int t = 0; t < 2; ++t)
            gl_lds16(Kp + (size_t)(kb + 4 * t + krow_l) * 32 + l4 * 8,
                     (char*)&kT[bf][h][t][0][0]);
        // V: 2 chunks (d rows 16j+rho)
        #pragma unroll
        for (int j = 0; j < 2; ++j)
            gl_lds16(Vp + (size_t)(16 * j + rho) * 2048 + kb + l4 * 8,
                     (char*)&vT[bf][h][16 * j][0]);
    };

    stage(0);

    #pragma unroll 2
    for (int it = 0; it < 16; ++it) {
        const int bf = it & 1;
        if (it < 15) {
            stage(it + 1);
            // stage(it) done; stage(it+1)'s 7/6 loads stay in flight
            if (h < 2) { asm volatile("s_waitcnt vmcnt(7)" ::: "memory"); }
            else       { asm volatile("s_waitcnt vmcnt(6)" ::: "memory"); }
        } else {
            asm volatile("s_waitcnt vmcnt(0)" ::: "memory");
        }
        __builtin_amdgcn_sched_barrier(0);
        __builtin_amdgcn_s_barrier();            // tile it visible to all waves

        // ---- LDS -> regs (swizzled reads for bias/nbias) ----
        f32x4 bb[2], nn[2];
        #pragma unroll
        for (int t = 0; t < 2; ++t) {
            int off = q16 * 128 + ((t * 16 + g * 32) ^ ((q16 & 7) << 4));
            bb[t] = *(const f32x4*)((const char*)&biasT[bf][0][0] + off);
            nn[t] = *(const f32x4*)((const char*)&nbT[bf][h][0][0] + off);
        }
        bf16x8 kf0 = *(const bf16x8*)((const char*)&kT[bf][h][0][0][0] + q16 * 64 + g * 16);
        bf16x8 kf1 = *(const bf16x8*)((const char*)&kT[bf][h][1][0][0] + q16 * 64 + g * 16);
        bf16x8 vf0 = *(const bf16x8*)((const char*)&vT[bf][h][q16][0] + g * 16);
        bf16x8 vf1 = *(const bf16x8*)((const char*)&vT[bf][h][16 + q16][0] + g * 16);
        asm volatile("s_waitcnt lgkmcnt(0)" ::: "memory");
        __builtin_amdgcn_sched_barrier(0);
        __builtin_amdgcn_s_barrier();            // buf[bf] free for it+2's stage

        // ---- compute (register-only) ----
        f32x4 z = {0, 0, 0, 0};
        f32x4 s0 = MFMA(kf0, qfrag, z);          // s0[i] = S[kb+8g+i][q16]
        f32x4 s1 = MFMA(kf1, qfrag, z);          // s1[i] = S[kb+4+8g+i][q16]
        s0 += bb[0] + nn[0];
        s1 += bb[1] + nn[1];

        float mx = fmaxf(fmaxf(fmaxf(s0[0], s0[1]), fmaxf(s0[2], s0[3])),
                         fmaxf(fmaxf(s1[0], s1[1]), fmaxf(s1[2], s1[3])));
        mx = fmaxf(mx, __shfl_xor(mx, 16));
        mx = fmaxf(mx, __shfl_xor(mx, 32));
        float m_new = fmaxf(m, mx);
        float alpha = __expf(m - m_new);
        float ps = 0.f;
        #pragma unroll
        for (int i = 0; i < 4; ++i) { s0[i] = __expf(s0[i] - m_new); ps += s0[i]; }
        #pragma unroll
        for (int i = 0; i < 4; ++i) { s1[i] = __expf(s1[i] - m_new); ps += s1[i]; }
        ps += __shfl_xor(ps, 16);
        ps += __shfl_xor(ps, 32);
        lsum = lsum * alpha + ps;
        m = m_new;

        // P -> PV B-fragment (register-only, sigma-aligned)
        u32x4 pc = { cvt_pk(s0[0], s0[1]), cvt_pk(s0[2], s0[3]),
                     cvt_pk(s1[0], s1[1]), cvt_pk(s1[2], s1[3]) };
        bf16x8 p = __builtin_bit_cast(bf16x8, pc);

        acc0 *= alpha;
        acc1 *= alpha;
        acc0 = MFMA(vf0, p, acc0);               // lane: out[q16][d=4g+i]
        acc1 = MFMA(vf1, p, acc1);               // lane: out[q16][d=16+4g+i]
    }

    // ---- epilogue: write UNNORMALIZED partials (m, l uniform across g) ----
    const size_t pidx = ((size_t)split * 16 + bh) * 2048 + (qb + q16);
    if (g == 0) { Pm[pidx] = m; Pl[pidx] = lsum; }
    float* pa = Pacc + pidx * 32;
    #pragma unroll
    for (int i = 0; i < 4; ++i) {
        pa[4 * g + i]      = acc0[i];
        pa[16 + 4 * g + i] = acc1[i];
    }
}

// ---------------------------------------------------------------------------
// Kernel 3: merge 4 kv-split partials (r2-proven math), normalize, gate,
// write bf16 WA.  512 blocks x 256 threads (4 waves = 4 heads, 16 q rows).
// ---------------------------------------------------------------------------
__global__ __launch_bounds__(256) void combine_kernel(
    const float* __restrict__ Pm, const float* __restrict__ Pl,
    const float* __restrict__ Pacc, const float* __restrict__ gate,
    unsigned short* __restrict__ WA)
{
    const int b  = blockIdx.x >> 7;
    const int qb = (blockIdx.x & 127) * 16;
    const int h    = threadIdx.x >> 6;
    const int lane = threadIdx.x & 63;
    const int q16 = lane & 15, g = lane >> 4;
    const size_t bh = (size_t)(b * 4 + h);
    const size_t q  = (size_t)(qb + q16);

    float ms[4], ls[4];
    #pragma unroll
    for (int s = 0; s < 4; ++s) {
        size_t idx = ((size_t)s * 16 + bh) * 2048 + q;
        ms[s] = Pm[idx];
        ls[s] = Pl[idx];
    }
    float M = fmaxf(fmaxf(ms[0], ms[1]), fmaxf(ms[2], ms[3]));
    float e[4];
    float L = 0.f;
    #pragma unroll
    for (int s = 0; s < 4; ++s) { e[s] = __expf(ms[s] - M); L += ls[s] * e[s]; }

    f32x4 o0 = {0, 0, 0, 0}, o1 = {0, 0, 0, 0};
    #pragma unroll
    for (int s = 0; s < 4; ++s) {
        const float* pa = Pacc + (((size_t)s * 16 + bh) * 2048 + q) * 32;
        f32x4 a0 = *(const f32x4*)(pa + 4 * g);
        f32x4 a1 = *(const f32x4*)(pa + 16 + 4 * g);
        o0 += a0 * e[s];
        o1 += a1 * e[s];
    }
    float invL = 1.0f / L;
    const float* grow = gate + ((size_t)b * 2048 + q) * 128 + h * 32;
    f32x4 g0 = *(const f32x4*)(grow + 4 * g);
    f32x4 g1 = *(const f32x4*)(grow + 16 + 4 * g);
    uint2 t0, t1;
    t0.x = cvt_pk(o0[0] * invL * g0[0], o0[1] * invL * g0[1]);
    t0.y = cvt_pk(o0[2] * invL * g0[2], o0[3] * invL * g0[3]);
    t1.x = cvt_pk(o1[0] * invL * g1[0], o1[1] * invL * g1[1]);
    t1.y = cvt_pk(o1[2] * invL * g1[2], o1[3] * invL * g1[3]);
    unsigned short* wrow = WA + ((size_t)b * 2048 + q) * 128 + h * 32;
    *(uint2*)(wrow + 4 * g)      = t0;
    *(uint2*)(wrow + 16 + 4 * g) = t1;
}

// ---------------------------------------------------------------------------
// Kernel 4: out = wa @ Wo + bo (verbatim round-6, proven).
// ---------------------------------------------------------------------------
__global__ __launch_bounds__(256) void outproj_kernel(
    const unsigned short* __restrict__ WA, const float* __restrict__ Wo,
    const float* __restrict__ bo, float* __restrict__ out)
{
    const int mtile = blockIdx.x;
    const int wave = threadIdx.x >> 6;
    const int lane = threadIdx.x & 63;
    const int r16 = lane & 15, g = lane >> 4;
    const int rowbase = mtile * 64 + wave * 16;

    bf16x8 afrag[4];
    #pragma unroll
    for (int kk = 0; kk < 4; ++kk)
        afrag[kk] = *(const bf16x8*)(WA + (size_t)(rowbase + r16) * 128 + kk * 32 + g * 8);

    #pragma unroll
    for (int n0 = 0; n0 < 8; ++n0) {
        f32x4 a = {0.f, 0.f, 0.f, 0.f};
        #pragma unroll
        for (int kk = 0; kk < 4; ++kk) {
            f32x4 lo, hi;
            #pragma unroll
            for (int i = 0; i < 4; ++i) {
                int k0 = kk * 32 + g * 8 + i;
                lo[i] = Wo[(size_t)k0 * 128 + n0 * 16 + r16];
                hi[i] = Wo[(size_t)(k0 + 4) * 128 + n0 * 16 + r16];
            }
            a = MFMA(afrag[kk], pack8(lo, hi), a);
        }
        float bov = bo[n0 * 16 + r16];
        #pragma unroll
        for (int i = 0; i < 4; ++i)
            out[(size_t)(rowbase + 4 * g + i) * 128 + n0 * 16 + r16] = a[i] + bov;
    }
}

// ---------------------------------------------------------------------------
extern "C" void kernel_launch(void* const* d_in, const int* in_sizes, int n_in,
                              void* d_out, int out_size, void* d_ws, size_t ws_size,
                              hipStream_t stream)
{
    const float* q_data = (const float*)d_in[0];
    const float* m_data = (const float*)d_in[1];
    const float* bias   = (const float*)d_in[2];
    const float* nbias  = (const float*)d_in[3];
    const float* Wq     = (const float*)d_in[4];
    const float* Wk     = (const float*)d_in[5];
    const float* Wv     = (const float*)d_in[6];
    const float* Wg     = (const float*)d_in[7];
    const float* bg     = (const float*)d_in[8];
    const float* Wo     = (const float*)d_in[9];
    const float* bo     = (const float*)d_in[10];
    float* out = (float*)d_out;

    char* ws = (char*)d_ws;
    unsigned short* Qb = (unsigned short*)(ws);                  //  0MB, 2MB
    unsigned short* Kb = (unsigned short*)(ws + (2u << 20));     //  2MB, 2MB
    unsigned short* VT = (unsigned short*)(ws + (4u << 20));     //  4MB, 2MB
    float*          gate = (float*)(ws + (6u << 20));            //  6MB, 4MB
    unsigned short* WA = (unsigned short*)(ws + (10u << 20));    // 10MB, 2MB
    float*          Pm = (float*)(ws + (12u << 20));             // 12MB, .5MB
    float*          Pl = (float*)(ws + (12u << 20) + (512u << 10)); // .5MB
    float*          Pacc = (float*)(ws + (13u << 20));           // 13MB, 16MB

    proj_kernel<<<dim3(512), dim3(256), 0, stream>>>(
        q_data, m_data, Wq, Wk, Wv, Wg, bg, Qb, Kb, VT, gate);
    attn_kernel<<<dim3(2048), dim3(256), 0, stream>>>(
        Qb, Kb, VT, bias, nbias, Pm, Pl, Pacc);
    combine_kernel<<<dim3(512), dim3(256), 0, stream>>>(
        Pm, Pl, Pacc, gate, WA);
    outproj_kernel<<<dim3(128), dim3(256), 0, stream>>>(
        WA, Wo, bo, out);
}

// Round 10
// 83.079 us; speedup vs baseline: 1.2226x; 1.0986x over previous
//
#include <hip/hip_runtime.h>
#include <cstdint>
#include <cstddef>

typedef __bf16 bf16x8 __attribute__((ext_vector_type(8)));
typedef unsigned short u16x8 __attribute__((ext_vector_type(8)));
typedef float f32x4 __attribute__((ext_vector_type(4)));
typedef unsigned u32x4 __attribute__((ext_vector_type(4)));

#define MFMA(a, b, c) __builtin_amdgcn_mfma_f32_16x16x32_bf16(a, b, c, 0, 0, 0)
#define WAITV(N) asm volatile("s_waitcnt vmcnt(" #N ")" ::: "memory")
#define SBAR()   __builtin_amdgcn_sched_barrier(0)

__device__ __forceinline__ unsigned short f2bfbits(float x) {
    unsigned u = __builtin_bit_cast(unsigned, x);
    u += 0x7FFFu + ((u >> 16) & 1u);           // round-to-nearest-even
    return (unsigned short)(u >> 16);
}

// HW packed f32->bf16 (RNE)
__device__ __forceinline__ unsigned cvt_pk(float lo, float hi) {
    unsigned r;
    asm("v_cvt_pk_bf16_f32 %0, %1, %2" : "=v"(r) : "v"(lo), "v"(hi));
    return r;
}

__device__ __forceinline__ bf16x8 pack8(f32x4 a, f32x4 b) {
    u32x4 t = { cvt_pk(a[0], a[1]), cvt_pk(a[2], a[3]),
                cvt_pk(b[0], b[1]), cvt_pk(b[2], b[3]) };
    return __builtin_bit_cast(bf16x8, t);
}

// async global->LDS DMA, 16B/lane; LDS dest = wave-uniform base + lane*16.
__device__ __forceinline__ void gl_lds16(const void* g, void* l) {
    __builtin_amdgcn_global_load_lds(
        (const __attribute__((address_space(1))) unsigned int*)g,
        (__attribute__((address_space(3))) unsigned int*)l, 16, 0, 0);
}

// ---------------------------------------------------------------------------
// Kernel 1: projections (unchanged; proven rounds 1-9).
// ---------------------------------------------------------------------------
__global__ __launch_bounds__(256) void proj_kernel(
    const float* __restrict__ q_data, const float* __restrict__ m_data,
    const float* __restrict__ Wq, const float* __restrict__ Wk,
    const float* __restrict__ Wv, const float* __restrict__ Wg,
    const float* __restrict__ bg,
    unsigned short* __restrict__ Qb, unsigned short* __restrict__ Kb,
    unsigned short* __restrict__ VT, float* __restrict__ gate)
{
    __shared__ unsigned short vt_lds[128][80];
    const int mat   = blockIdx.x >> 7;
    const int mtile = blockIdx.x & 127;
    const int wave  = threadIdx.x >> 6;
    const int lane  = threadIdx.x & 63;
    const int r16 = lane & 15, g = lane >> 4;
    const int rowbase = mtile * 64 + wave * 16;

    const float* src = (mat == 1 || mat == 2) ? m_data : q_data;
    const float* W   = (mat == 0) ? Wq : (mat == 1) ? Wk : (mat == 2) ? Wv : Wg;

    bf16x8 afrag[4];
    {
        const float* arow = src + (size_t)(rowbase + r16) * 128;
        #pragma unroll
        for (int kk = 0; kk < 4; ++kk) {
            f32x4 lo = *(const f32x4*)(arow + kk * 32 + g * 8);
            f32x4 hi = *(const f32x4*)(arow + kk * 32 + g * 8 + 4);
            afrag[kk] = pack8(lo, hi);
        }
    }

    f32x4 acc[8];
    #pragma unroll
    for (int n0 = 0; n0 < 8; ++n0) {
        f32x4 a = {0.f, 0.f, 0.f, 0.f};
        #pragma unroll
        for (int kk = 0; kk < 4; ++kk) {
            f32x4 lo, hi;
            #pragma unroll
            for (int i = 0; i < 4; ++i) {
                lo[i] = W[(size_t)(kk * 32 + g * 8 + i) * 128 + n0 * 16 + r16];
                hi[i] = W[(size_t)(kk * 32 + g * 8 + 4 + i) * 128 + n0 * 16 + r16];
            }
            a = MFMA(afrag[kk], pack8(lo, hi), a);
        }
        acc[n0] = a;
    }

    if (mat <= 1) {
        unsigned short* dst = (mat == 0) ? Qb : Kb;
        #pragma unroll
        for (int n0 = 0; n0 < 8; ++n0) {
            int n = n0 * 16 + r16, h = n >> 5, d = n & 31;
            #pragma unroll
            for (int i = 0; i < 4; ++i) {
                int grow = rowbase + 4 * g + i;
                int bb = grow >> 11, ns = grow & 2047;
                dst[(size_t)(bb * 4 + h) * 65536 + (size_t)ns * 32 + d] =
                    f2bfbits(acc[n0][i]);
            }
        }
    } else if (mat == 2) {
        #pragma unroll
        for (int n0 = 0; n0 < 8; ++n0) {
            int n = n0 * 16 + r16;
            #pragma unroll
            for (int i = 0; i < 4; ++i)
                vt_lds[n][wave * 16 + 4 * g + i] = f2bfbits(acc[n0][i]);
        }
        __syncthreads();
        int bb = rowbase >> 11;
        int nsbase = (mtile * 64) & 2047;
        #pragma unroll
        for (int it = 0; it < 4; ++it) {
            int idx = (threadIdx.x + it * 256) * 8;
            int n = idx >> 6, mm = idx & 63;
            u16x8 v = *(const u16x8*)&vt_lds[n][mm];
            *(u16x8*)(VT + (size_t)(bb * 128 + n) * 2048 + nsbase + mm) = v;
        }
    } else {
        #pragma unroll
        for (int n0 = 0; n0 < 8; ++n0) {
            int n = n0 * 16 + r16;
            float bgv = bg[n];
            #pragma unroll
            for (int i = 0; i < 4; ++i) {
                int grow = rowbase + 4 * g + i;
                float x = acc[n0][i] + bgv;
                gate[(size_t)grow * 128 + n] = 1.0f / (1.0f + __expf(-x));
            }
        }
    }
}

// ---------------------------------------------------------------------------
// Kernel 2: flash attention partials, r9's proven machinery with bigger
// tiles: block = (split, b-pair, 32-q-tile); 512 blocks x 512 threads
// (8 waves = 4 heads x 2 q-halves); each wave runs the r9 chain for 2 b's.
// Staged bytes: 448MB vs r9's 851MB (K/V amp /2 via QB=32, nbias amp /2 via
// b-pair). Uniform 7 DMAs per wave per iter -> single vmcnt(7). All chunk
// shapes, swizzles, sigma-permutation, softmax chain: r9 VERBATIM.
// LDS ring-2 = 112KB dynamic.
// ---------------------------------------------------------------------------
#define NB_OFF 16384
#define K_OFF  49152
#define V_OFF  81920

__global__ __launch_bounds__(512, 2) void attn_kernel(
    const unsigned short* __restrict__ Qb, const unsigned short* __restrict__ Kb,
    const unsigned short* __restrict__ VT,
    const float* __restrict__ bias, const float* __restrict__ nbias,
    float* __restrict__ Pm, float* __restrict__ Pl, float* __restrict__ Pacc)
{
    extern __shared__ __align__(16) char pool[];   // 112KB, ring-2

    const int split = blockIdx.x >> 7;             // [0,4)
    const int rem   = blockIdx.x & 127;
    const int bpair = rem >> 6;                    // [0,2)
    const int qt32  = rem & 63;                    // [0,64)
    const int qb32  = qt32 * 32;
    const int kv0   = split * 512;

    const int w    = threadIdx.x >> 6;             // [0,8)
    const int h    = w & 3;
    const int qh   = w >> 2;                       // q-half
    const int lane = threadIdx.x & 63;
    const int q16 = lane & 15, g = lane >> 4;

    // staging lane decompositions (r9 verbatim)
    const int ls8 = lane >> 3, lc8 = lane & 7;        // bias/nbias chunks
    const int rho = lane >> 2, l4 = lane & 3;         // K/V chunks
    const int krow_l = ((rho >> 2) << 3) + (rho & 3); // sigma permutation

    // global bases
    const float* bias_bq = bias + ((size_t)((bpair * 2 + qh) * 2048 + qb32)) * 2048;
    const float* nb_h    = nbias + ((size_t)(h * 2048 + qb32)) * 2048;
    const unsigned short* Kp_own = Kb + (size_t)((bpair * 2 + qh) * 4 + h) * 65536;
    const unsigned short* Vp_own = VT + (size_t)((bpair * 2 + qh) * 4 + h) * 65536;

    // Q fragments for both local b's (plain loads; retired by first WAITV)
    bf16x8 qf0 = *(const bf16x8*)(Qb + (size_t)((bpair * 2 + 0) * 4 + h) * 65536
                                  + (size_t)(qb32 + qh * 16 + q16) * 32 + g * 8);
    bf16x8 qf1 = *(const bf16x8*)(Qb + (size_t)((bpair * 2 + 1) * 4 + h) * 65536
                                  + (size_t)(qb32 + qh * 16 + q16) * 32 + g * 8);

    float m0v = -1e30f, l0v = 0.f, m1v = -1e30f, l1v = 0.f;
    f32x4 a00 = {0, 0, 0, 0}, a01 = {0, 0, 0, 0};   // b=0: d 0-15, 16-31
    f32x4 a10 = {0, 0, 0, 0}, a11 = {0, 0, 0, 0};   // b=1

    // ---- stage tile it -> ring slot it&1; UNIFORM 7 DMAs on every wave ----
    auto stage = [&](int it) {
        if (it >= 16) return;
        const int bf = it & 1;
        const int kb = kv0 + it * 32;
        const int csw0 = (lc8 * 4) ^ (ls8 << 2);      // r9 chunk swizzle (f32)
        // bias: chunk c=h of local b=qh (rows qh-tile-local 8h..8h+7)  [1 DMA]
        gl_lds16(bias_bq + (size_t)(8 * h + ls8) * 2048 + kb + csw0,
                 pool + bf * 8192 + qh * 4096 + h * 1024);
        // nbias: own (h, q-half) rows qh*16+8c+ls8                     [2 DMA]
        #pragma unroll
        for (int c = 0; c < 2; ++c)
            gl_lds16(nb_h + (size_t)(qh * 16 + 8 * c + ls8) * 2048 + kb + csw0,
                     pool + NB_OFF + bf * 16384 + h * 4096 + qh * 2048 + c * 1024);
        // K: (b=qh, h), sigma-permuted (r9 verbatim)                   [2 DMA]
        #pragma unroll
        for (int t = 0; t < 2; ++t)
            gl_lds16(Kp_own + (size_t)(kb + 4 * t + krow_l) * 32 + l4 * 8,
                     pool + K_OFF + bf * 16384 + qh * 8192 + h * 2048 + t * 1024);
        // V: (b=qh, h) (r9 verbatim)                                   [2 DMA]
        #pragma unroll
        for (int j = 0; j < 2; ++j)
            gl_lds16(Vp_own + (size_t)(16 * j + rho) * 2048 + kb + l4 * 8,
                     pool + V_OFF + bf * 16384 + qh * 8192 + h * 2048 + j * 1024);
    };

    // ---- softmax+PV chain (r9 verbatim) ----
    auto chain = [&](f32x4 s0, f32x4 s1, bf16x8 vf0, bf16x8 vf1,
                     float& m, float& lsum, f32x4& ac0, f32x4& ac1) {
        float mx = fmaxf(fmaxf(fmaxf(s0[0], s0[1]), fmaxf(s0[2], s0[3])),
                         fmaxf(fmaxf(s1[0], s1[1]), fmaxf(s1[2], s1[3])));
        mx = fmaxf(mx, __shfl_xor(mx, 16));
        mx = fmaxf(mx, __shfl_xor(mx, 32));
        float m_new = fmaxf(m, mx);
        float alpha = __expf(m - m_new);
        float ps = 0.f;
        #pragma unroll
        for (int i = 0; i < 4; ++i) { s0[i] = __expf(s0[i] - m_new); ps += s0[i]; }
        #pragma unroll
        for (int i = 0; i < 4; ++i) { s1[i] = __expf(s1[i] - m_new); ps += s1[i]; }
        ps += __shfl_xor(ps, 16);
        ps += __shfl_xor(ps, 32);
        lsum = lsum * alpha + ps;
        m = m_new;
        u32x4 pc = { cvt_pk(s0[0], s0[1]), cvt_pk(s0[2], s0[3]),
                     cvt_pk(s1[0], s1[1]), cvt_pk(s1[2], s1[3]) };
        bf16x8 p = __builtin_bit_cast(bf16x8, pc);
        ac0 *= alpha;
        ac1 *= alpha;
        ac0 = MFMA(vf0, p, ac0);
        ac1 = MFMA(vf1, p, ac1);
    };

    stage(0);

    #pragma unroll 2
    for (int it = 0; it < 16; ++it) {
        const int bf = it & 1;
        if (it < 15) {
            stage(it + 1);
            WAITV(7);                            // stage(it) retired
        } else {
            WAITV(0);
        }
        SBAR();
        __builtin_amdgcn_s_barrier();            // tile it visible to all waves

        // ---- LDS -> regs (r9 read formulas; r = qh*16+q16, r&7 = q16&7) ----
        const int r128 = (qh * 16 + q16) * 128;
        const int rsw  = (q16 & 7) << 4;
        const char* np = pool + NB_OFF + bf * 16384 + h * 4096;
        f32x4 nn0 = *(const f32x4*)(np + r128 + ((g * 32) ^ rsw));
        f32x4 nn1 = *(const f32x4*)(np + r128 + ((16 + g * 32) ^ rsw));
        const char* bp0 = pool + bf * 8192;
        f32x4 b00 = *(const f32x4*)(bp0 + r128 + ((g * 32) ^ rsw));
        f32x4 b01 = *(const f32x4*)(bp0 + r128 + ((16 + g * 32) ^ rsw));
        const char* bp1 = bp0 + 4096;
        f32x4 b10 = *(const f32x4*)(bp1 + r128 + ((g * 32) ^ rsw));
        f32x4 b11 = *(const f32x4*)(bp1 + r128 + ((16 + g * 32) ^ rsw));
        const char* kp0 = pool + K_OFF + bf * 16384 + h * 2048;
        bf16x8 kf00 = *(const bf16x8*)(kp0 + q16 * 64 + g * 16);
        bf16x8 kf01 = *(const bf16x8*)(kp0 + 1024 + q16 * 64 + g * 16);
        const char* kp1 = kp0 + 8192;
        bf16x8 kf10 = *(const bf16x8*)(kp1 + q16 * 64 + g * 16);
        bf16x8 kf11 = *(const bf16x8*)(kp1 + 1024 + q16 * 64 + g * 16);
        const char* vp0 = pool + V_OFF + bf * 16384 + h * 2048;
        bf16x8 vf00 = *(const bf16x8*)(vp0 + q16 * 64 + g * 16);
        bf16x8 vf01 = *(const bf16x8*)(vp0 + 1024 + q16 * 64 + g * 16);
        const char* vp1 = vp0 + 8192;
        bf16x8 vf10 = *(const bf16x8*)(vp1 + q16 * 64 + g * 16);
        bf16x8 vf11 = *(const bf16x8*)(vp1 + 1024 + q16 * 64 + g * 16);
        asm volatile("s_waitcnt lgkmcnt(0)" ::: "memory");
        SBAR();
        __builtin_amdgcn_s_barrier();            // buf bf free for it+2's stage

        // ---- compute: two independent r9 chains ----
        f32x4 z = {0, 0, 0, 0};
        f32x4 s00 = MFMA(kf00, qf0, z);          // b=0
        f32x4 s01 = MFMA(kf01, qf0, z);
        s00 += b00 + nn0;
        s01 += b01 + nn1;
        f32x4 s10 = MFMA(kf10, qf1, z);          // b=1
        f32x4 s11 = MFMA(kf11, qf1, z);
        s10 += b10 + nn0;
        s11 += b11 + nn1;
        chain(s00, s01, vf00, vf01, m0v, l0v, a00, a01);
        chain(s10, s11, vf10, vf11, m1v, l1v, a10, a11);
    }

    // ---- epilogue: write UNNORMALIZED partials for both b's ----
    {
        const size_t q = (size_t)(qb32 + qh * 16 + q16);
        const size_t p0 = ((size_t)split * 16 + (bpair * 2 + 0) * 4 + h) * 2048 + q;
        const size_t p1 = ((size_t)split * 16 + (bpair * 2 + 1) * 4 + h) * 2048 + q;
        if (g == 0) { Pm[p0] = m0v; Pl[p0] = l0v; Pm[p1] = m1v; Pl[p1] = l1v; }
        float* pa0 = Pacc + p0 * 32;
        float* pa1 = Pacc + p1 * 32;
        #pragma unroll
        for (int i = 0; i < 4; ++i) {
            pa0[4 * g + i]      = a00[i];
            pa0[16 + 4 * g + i] = a01[i];
            pa1[4 * g + i]      = a10[i];
            pa1[16 + 4 * g + i] = a11[i];
        }
    }
}

// ---------------------------------------------------------------------------
// Kernel 3: merge 4 kv-split partials, normalize, gate, write bf16 WA.
// (r9 verbatim, proven.)
// ---------------------------------------------------------------------------
__global__ __launch_bounds__(256) void combine_kernel(
    const float* __restrict__ Pm, const float* __restrict__ Pl,
    const float* __restrict__ Pacc, const float* __restrict__ gate,
    unsigned short* __restrict__ WA)
{
    const int b  = blockIdx.x >> 7;
    const int qb = (blockIdx.x & 127) * 16;
    const int h    = threadIdx.x >> 6;
    const int lane = threadIdx.x & 63;
    const int q16 = lane & 15, g = lane >> 4;
    const size_t bh = (size_t)(b * 4 + h);
    const size_t q  = (size_t)(qb + q16);

    float ms[4], ls[4];
    #pragma unroll
    for (int s = 0; s < 4; ++s) {
        size_t idx = ((size_t)s * 16 + bh) * 2048 + q;
        ms[s] = Pm[idx];
        ls[s] = Pl[idx];
    }
    float M = fmaxf(fmaxf(ms[0], ms[1]), fmaxf(ms[2], ms[3]));
    float e[4];
    float L = 0.f;
    #pragma unroll
    for (int s = 0; s < 4; ++s) { e[s] = __expf(ms[s] - M); L += ls[s] * e[s]; }

    f32x4 o0 = {0, 0, 0, 0}, o1 = {0, 0, 0, 0};
    #pragma unroll
    for (int s = 0; s < 4; ++s) {
        const float* pa = Pacc + (((size_t)s * 16 + bh) * 2048 + q) * 32;
        f32x4 a0 = *(const f32x4*)(pa + 4 * g);
        f32x4 a1 = *(const f32x4*)(pa + 16 + 4 * g);
        o0 += a0 * e[s];
        o1 += a1 * e[s];
    }
    float invL = 1.0f / L;
    const float* grow = gate + ((size_t)b * 2048 + q) * 128 + h * 32;
    f32x4 g0 = *(const f32x4*)(grow + 4 * g);
    f32x4 g1 = *(const f32x4*)(grow + 16 + 4 * g);
    uint2 t0, t1;
    t0.x = cvt_pk(o0[0] * invL * g0[0], o0[1] * invL * g0[1]);
    t0.y = cvt_pk(o0[2] * invL * g0[2], o0[3] * invL * g0[3]);
    t1.x = cvt_pk(o1[0] * invL * g1[0], o1[1] * invL * g1[1]);
    t1.y = cvt_pk(o1[2] * invL * g1[2], o1[3] * invL * g1[3]);
    unsigned short* wrow = WA + ((size_t)b * 2048 + q) * 128 + h * 32;
    *(uint2*)(wrow + 4 * g)      = t0;
    *(uint2*)(wrow + 16 + 4 * g) = t1;
}

// ---------------------------------------------------------------------------
// Kernel 4: out = wa @ Wo + bo (r6/r9 verbatim, proven).
// ---------------------------------------------------------------------------
__global__ __launch_bounds__(256) void outproj_kernel(
    const unsigned short* __restrict__ WA, const float* __restrict__ Wo,
    const float* __restrict__ bo, float* __restrict__ out)
{
    const int mtile = blockIdx.x;
    const int wave = threadIdx.x >> 6;
    const int lane = threadIdx.x & 63;
    const int r16 = lane & 15, g = lane >> 4;
    const int rowbase = mtile * 64 + wave * 16;

    bf16x8 afrag[4];
    #pragma unroll
    for (int kk = 0; kk < 4; ++kk)
        afrag[kk] = *(const bf16x8*)(WA + (size_t)(rowbase + r16) * 128 + kk * 32 + g * 8);

    #pragma unroll
    for (int n0 = 0; n0 < 8; ++n0) {
        f32x4 a = {0.f, 0.f, 0.f, 0.f};
        #pragma unroll
        for (int kk = 0; kk < 4; ++kk) {
            f32x4 lo, hi;
            #pragma unroll
            for (int i = 0; i < 4; ++i) {
                int k0 = kk * 32 + g * 8 + i;
                lo[i] = Wo[(size_t)k0 * 128 + n0 * 16 + r16];
                hi[i] = Wo[(size_t)(k0 + 4) * 128 + n0 * 16 + r16];
            }
            a = MFMA(afrag[kk], pack8(lo, hi), a);
        }
        float bov = bo[n0 * 16 + r16];
        #pragma unroll
        for (int i = 0; i < 4; ++i)
            out[(size_t)(rowbase + 4 * g + i) * 128 + n0 * 16 + r16] = a[i] + bov;
    }
}

// ---------------------------------------------------------------------------
extern "C" void kernel_launch(void* const* d_in, const int* in_sizes, int n_in,
                              void* d_out, int out_size, void* d_ws, size_t ws_size,
                              hipStream_t stream)
{
    const float* q_data = (const float*)d_in[0];
    const float* m_data = (const float*)d_in[1];
    const float* bias   = (const float*)d_in[2];
    const float* nbias  = (const float*)d_in[3];
    const float* Wq     = (const float*)d_in[4];
    const float* Wk     = (const float*)d_in[5];
    const float* Wv     = (const float*)d_in[6];
    const float* Wg     = (const float*)d_in[7];
    const float* bg     = (const float*)d_in[8];
    const float* Wo     = (const float*)d_in[9];
    const float* bo     = (const float*)d_in[10];
    float* out = (float*)d_out;

    char* ws = (char*)d_ws;
    unsigned short* Qb = (unsigned short*)(ws);                  //  0MB, 2MB
    unsigned short* Kb = (unsigned short*)(ws + (2u << 20));     //  2MB, 2MB
    unsigned short* VT = (unsigned short*)(ws + (4u << 20));     //  4MB, 2MB
    float*          gate = (float*)(ws + (6u << 20));            //  6MB, 4MB
    unsigned short* WA = (unsigned short*)(ws + (10u << 20));    // 10MB, 2MB
    float*          Pm = (float*)(ws + (12u << 20));             // 12MB, .5MB
    float*          Pl = (float*)(ws + (12u << 20) + (512u << 10)); // .5MB
    float*          Pacc = (float*)(ws + (13u << 20));           // 13MB, 16MB

    proj_kernel<<<dim3(512), dim3(256), 0, stream>>>(
        q_data, m_data, Wq, Wk, Wv, Wg, bg, Qb, Kb, VT, gate);
    attn_kernel<<<dim3(512), dim3(512), 114688, stream>>>(
        Qb, Kb, VT, bias, nbias, Pm, Pl, Pacc);
    combine_kernel<<<dim3(512), dim3(256), 0, stream>>>(
        Pm, Pl, Pacc, gate, WA);
    outproj_kernel<<<dim3(128), dim3(256), 0, stream>>>(
        WA, Wo, bo, out);
}

// Round 15
// 81.856 us; speedup vs baseline: 1.2409x; 1.0149x over previous
//
#include <hip/hip_runtime.h>
#include <cstdint>
#include <cstddef>

typedef __bf16 bf16x8 __attribute__((ext_vector_type(8)));
typedef unsigned short u16x8 __attribute__((ext_vector_type(8)));
typedef float f32x4 __attribute__((ext_vector_type(4)));
typedef unsigned u32x4 __attribute__((ext_vector_type(4)));

#define MFMA(a, b, c) __builtin_amdgcn_mfma_f32_16x16x32_bf16(a, b, c, 0, 0, 0)
#define WAITV(N) asm volatile("s_waitcnt vmcnt(" #N ")" ::: "memory")
#define SBAR()   __builtin_amdgcn_sched_barrier(0)

__device__ __forceinline__ unsigned short f2bfbits(float x) {
    unsigned u = __builtin_bit_cast(unsigned, x);
    u += 0x7FFFu + ((u >> 16) & 1u);           // round-to-nearest-even
    return (unsigned short)(u >> 16);
}

// HW packed f32->bf16 (RNE)
__device__ __forceinline__ unsigned cvt_pk(float lo, float hi) {
    unsigned r;
    asm("v_cvt_pk_bf16_f32 %0, %1, %2" : "=v"(r) : "v"(lo), "v"(hi));
    return r;
}

__device__ __forceinline__ bf16x8 pack8(f32x4 a, f32x4 b) {
    u32x4 t = { cvt_pk(a[0], a[1]), cvt_pk(a[2], a[3]),
                cvt_pk(b[0], b[1]), cvt_pk(b[2], b[3]) };
    return __builtin_bit_cast(bf16x8, t);
}

// async global->LDS DMA, 16B/lane; LDS dest = wave-uniform base + lane*16.
__device__ __forceinline__ void gl_lds16(const void* g, void* l) {
    __builtin_amdgcn_global_load_lds(
        (const __attribute__((address_space(1))) unsigned int*)g,
        (__attribute__((address_space(3))) unsigned int*)l, 16, 0, 0);
}

// ---------------------------------------------------------------------------
// Kernel 1: projections (r10 verbatim; proven rounds 1-10).
// ---------------------------------------------------------------------------
__global__ __launch_bounds__(256) void proj_kernel(
    const float* __restrict__ q_data, const float* __restrict__ m_data,
    const float* __restrict__ Wq, const float* __restrict__ Wk,
    const float* __restrict__ Wv, const float* __restrict__ Wg,
    const float* __restrict__ bg,
    unsigned short* __restrict__ Qb, unsigned short* __restrict__ Kb,
    unsigned short* __restrict__ VT, float* __restrict__ gate)
{
    __shared__ unsigned short vt_lds[128][80];
    const int mat   = blockIdx.x >> 7;
    const int mtile = blockIdx.x & 127;
    const int wave  = threadIdx.x >> 6;
    const int lane  = threadIdx.x & 63;
    const int r16 = lane & 15, g = lane >> 4;
    const int rowbase = mtile * 64 + wave * 16;

    const float* src = (mat == 1 || mat == 2) ? m_data : q_data;
    const float* W   = (mat == 0) ? Wq : (mat == 1) ? Wk : (mat == 2) ? Wv : Wg;

    bf16x8 afrag[4];
    {
        const float* arow = src + (size_t)(rowbase + r16) * 128;
        #pragma unroll
        for (int kk = 0; kk < 4; ++kk) {
            f32x4 lo = *(const f32x4*)(arow + kk * 32 + g * 8);
            f32x4 hi = *(const f32x4*)(arow + kk * 32 + g * 8 + 4);
            afrag[kk] = pack8(lo, hi);
        }
    }

    f32x4 acc[8];
    #pragma unroll
    for (int n0 = 0; n0 < 8; ++n0) {
        f32x4 a = {0.f, 0.f, 0.f, 0.f};
        #pragma unroll
        for (int kk = 0; kk < 4; ++kk) {
            f32x4 lo, hi;
            #pragma unroll
            for (int i = 0; i < 4; ++i) {
                lo[i] = W[(size_t)(kk * 32 + g * 8 + i) * 128 + n0 * 16 + r16];
                hi[i] = W[(size_t)(kk * 32 + g * 8 + 4 + i) * 128 + n0 * 16 + r16];
            }
            a = MFMA(afrag[kk], pack8(lo, hi), a);
        }
        acc[n0] = a;
    }

    if (mat <= 1) {
        unsigned short* dst = (mat == 0) ? Qb : Kb;
        #pragma unroll
        for (int n0 = 0; n0 < 8; ++n0) {
            int n = n0 * 16 + r16, h = n >> 5, d = n & 31;
            #pragma unroll
            for (int i = 0; i < 4; ++i) {
                int grow = rowbase + 4 * g + i;
                int bb = grow >> 11, ns = grow & 2047;
                dst[(size_t)(bb * 4 + h) * 65536 + (size_t)ns * 32 + d] =
                    f2bfbits(acc[n0][i]);
            }
        }
    } else if (mat == 2) {
        #pragma unroll
        for (int n0 = 0; n0 < 8; ++n0) {
            int n = n0 * 16 + r16;
            #pragma unroll
            for (int i = 0; i < 4; ++i)
                vt_lds[n][wave * 16 + 4 * g + i] = f2bfbits(acc[n0][i]);
        }
        __syncthreads();
        int bb = rowbase >> 11;
        int nsbase = (mtile * 64) & 2047;
        #pragma unroll
        for (int it = 0; it < 4; ++it) {
            int idx = (threadIdx.x + it * 256) * 8;
            int n = idx >> 6, mm = idx & 63;
            u16x8 v = *(const u16x8*)&vt_lds[n][mm];
            *(u16x8*)(VT + (size_t)(bb * 128 + n) * 2048 + nsbase + mm) = v;
        }
    } else {
        #pragma unroll
        for (int n0 = 0; n0 < 8; ++n0) {
            int n = n0 * 16 + r16;
            float bgv = bg[n];
            #pragma unroll
            for (int i = 0; i < 4; ++i) {
                int grow = rowbase + 4 * g + i;
                float x = acc[n0][i] + bgv;
                gate[(size_t)grow * 128 + n] = 1.0f / (1.0f + __expf(-x));
            }
        }
    }
}

// ---------------------------------------------------------------------------
// Kernel 2: flash attention partials (r10 VERBATIM - passed at 83.1us).
// Block = (split, bpair, qt32): 512 blocks x 512 threads (8 waves = 2
// q-halves x 4 heads); each wave runs the r9 chain for 2 b's.  Ring-2 LDS
// 112KB dynamic, all loop VMEM = global_load_lds DMA, uniform 7 DMAs/wave,
// counted WAITV(7), 2 barriers/iter.
// ---------------------------------------------------------------------------
#define NB_OFF 16384
#define K_OFF  49152
#define V_OFF  81920

__global__ __launch_bounds__(512, 2) void attn_kernel(
    const unsigned short* __restrict__ Qb, const unsigned short* __restrict__ Kb,
    const unsigned short* __restrict__ VT,
    const float* __restrict__ bias, const float* __restrict__ nbias,
    float* __restrict__ Pm, float* __restrict__ Pl, float* __restrict__ Pacc)
{
    extern __shared__ __align__(16) char pool[];   // 112KB, ring-2

    const int split = blockIdx.x >> 7;             // [0,4)
    const int rem   = blockIdx.x & 127;
    const int bpair = rem >> 6;                    // [0,2)
    const int qt32  = rem & 63;                    // [0,64)
    const int qb32  = qt32 * 32;
    const int kv0   = split * 512;

    const int w    = threadIdx.x >> 6;             // [0,8)
    const int h    = w & 3;
    const int qh   = w >> 2;                       // q-half
    const int lane = threadIdx.x & 63;
    const int q16 = lane & 15, g = lane >> 4;

    // staging lane decompositions (r9 verbatim)
    const int ls8 = lane >> 3, lc8 = lane & 7;        // bias/nbias chunks
    const int rho = lane >> 2, l4 = lane & 3;         // K/V chunks
    const int krow_l = ((rho >> 2) << 3) + (rho & 3); // sigma permutation

    // global bases
    const float* bias_bq = bias + ((size_t)((bpair * 2 + qh) * 2048 + qb32)) * 2048;
    const float* nb_h    = nbias + ((size_t)(h * 2048 + qb32)) * 2048;
    const unsigned short* Kp_own = Kb + (size_t)((bpair * 2 + qh) * 4 + h) * 65536;
    const unsigned short* Vp_own = VT + (size_t)((bpair * 2 + qh) * 4 + h) * 65536;

    // Q fragments for both local b's (plain loads; retired by first WAITV)
    bf16x8 qf0 = *(const bf16x8*)(Qb + (size_t)((bpair * 2 + 0) * 4 + h) * 65536
                                  + (size_t)(qb32 + qh * 16 + q16) * 32 + g * 8);
    bf16x8 qf1 = *(const bf16x8*)(Qb + (size_t)((bpair * 2 + 1) * 4 + h) * 65536
                                  + (size_t)(qb32 + qh * 16 + q16) * 32 + g * 8);

    float m0v = -1e30f, l0v = 0.f, m1v = -1e30f, l1v = 0.f;
    f32x4 a00 = {0, 0, 0, 0}, a01 = {0, 0, 0, 0};   // b=0: d 0-15, 16-31
    f32x4 a10 = {0, 0, 0, 0}, a11 = {0, 0, 0, 0};   // b=1

    // ---- stage tile it -> ring slot it&1; UNIFORM 7 DMAs on every wave ----
    auto stage = [&](int it) {
        if (it >= 16) return;
        const int bf = it & 1;
        const int kb = kv0 + it * 32;
        const int csw0 = (lc8 * 4) ^ (ls8 << 2);      // r9 chunk swizzle (f32)
        // bias: chunk c=h of local b=qh (rows qh-tile-local 8h..8h+7)  [1 DMA]
        gl_lds16(bias_bq + (size_t)(8 * h + ls8) * 2048 + kb + csw0,
                 pool + bf * 8192 + qh * 4096 + h * 1024);
        // nbias: own (h, q-half) rows qh*16+8c+ls8                     [2 DMA]
        #pragma unroll
        for (int c = 0; c < 2; ++c)
            gl_lds16(nb_h + (size_t)(qh * 16 + 8 * c + ls8) * 2048 + kb + csw0,
                     pool + NB_OFF + bf * 16384 + h * 4096 + qh * 2048 + c * 1024);
        // K: (b=qh, h), sigma-permuted (r9 verbatim)                   [2 DMA]
        #pragma unroll
        for (int t = 0; t < 2; ++t)
            gl_lds16(Kp_own + (size_t)(kb + 4 * t + krow_l) * 32 + l4 * 8,
                     pool + K_OFF + bf * 16384 + qh * 8192 + h * 2048 + t * 1024);
        // V: (b=qh, h) (r9 verbatim)                                   [2 DMA]
        #pragma unroll
        for (int j = 0; j < 2; ++j)
            gl_lds16(Vp_own + (size_t)(16 * j + rho) * 2048 + kb + l4 * 8,
                     pool + V_OFF + bf * 16384 + qh * 8192 + h * 2048 + j * 1024);
    };

    // ---- softmax+PV chain (r9 verbatim) ----
    auto chain = [&](f32x4 s0, f32x4 s1, bf16x8 vf0, bf16x8 vf1,
                     float& m, float& lsum, f32x4& ac0, f32x4& ac1) {
        float mx = fmaxf(fmaxf(fmaxf(s0[0], s0[1]), fmaxf(s0[2], s0[3])),
                         fmaxf(fmaxf(s1[0], s1[1]), fmaxf(s1[2], s1[3])));
        mx = fmaxf(mx, __shfl_xor(mx, 16));
        mx = fmaxf(mx, __shfl_xor(mx, 32));
        float m_new = fmaxf(m, mx);
        float alpha = __expf(m - m_new);
        float ps = 0.f;
        #pragma unroll
        for (int i = 0; i < 4; ++i) { s0[i] = __expf(s0[i] - m_new); ps += s0[i]; }
        #pragma unroll
        for (int i = 0; i < 4; ++i) { s1[i] = __expf(s1[i] - m_new); ps += s1[i]; }
        ps += __shfl_xor(ps, 16);
        ps += __shfl_xor(ps, 32);
        lsum = lsum * alpha + ps;
        m = m_new;
        u32x4 pc = { cvt_pk(s0[0], s0[1]), cvt_pk(s0[2], s0[3]),
                     cvt_pk(s1[0], s1[1]), cvt_pk(s1[2], s1[3]) };
        bf16x8 p = __builtin_bit_cast(bf16x8, pc);
        ac0 *= alpha;
        ac1 *= alpha;
        ac0 = MFMA(vf0, p, ac0);
        ac1 = MFMA(vf1, p, ac1);
    };

    stage(0);

    #pragma unroll 2
    for (int it = 0; it < 16; ++it) {
        const int bf = it & 1;
        if (it < 15) {
            stage(it + 1);
            WAITV(7);                            // stage(it) retired
        } else {
            WAITV(0);
        }
        SBAR();
        __builtin_amdgcn_s_barrier();            // tile it visible to all waves

        // ---- LDS -> regs (r9 read formulas; r = qh*16+q16, r&7 = q16&7) ----
        const int r128 = (qh * 16 + q16) * 128;
        const int rsw  = (q16 & 7) << 4;
        const char* np = pool + NB_OFF + bf * 16384 + h * 4096;
        f32x4 nn0 = *(const f32x4*)(np + r128 + ((g * 32) ^ rsw));
        f32x4 nn1 = *(const f32x4*)(np + r128 + ((16 + g * 32) ^ rsw));
        const char* bp0 = pool + bf * 8192;
        f32x4 b00 = *(const f32x4*)(bp0 + r128 + ((g * 32) ^ rsw));
        f32x4 b01 = *(const f32x4*)(bp0 + r128 + ((16 + g * 32) ^ rsw));
        const char* bp1 = bp0 + 4096;
        f32x4 b10 = *(const f32x4*)(bp1 + r128 + ((g * 32) ^ rsw));
        f32x4 b11 = *(const f32x4*)(bp1 + r128 + ((16 + g * 32) ^ rsw));
        const char* kp0 = pool + K_OFF + bf * 16384 + h * 2048;
        bf16x8 kf00 = *(const bf16x8*)(kp0 + q16 * 64 + g * 16);
        bf16x8 kf01 = *(const bf16x8*)(kp0 + 1024 + q16 * 64 + g * 16);
        const char* kp1 = kp0 + 8192;
        bf16x8 kf10 = *(const bf16x8*)(kp1 + q16 * 64 + g * 16);
        bf16x8 kf11 = *(const bf16x8*)(kp1 + 1024 + q16 * 64 + g * 16);
        const char* vp0 = pool + V_OFF + bf * 16384 + h * 2048;
        bf16x8 vf00 = *(const bf16x8*)(vp0 + q16 * 64 + g * 16);
        bf16x8 vf01 = *(const bf16x8*)(vp0 + 1024 + q16 * 64 + g * 16);
        const char* vp1 = vp0 + 8192;
        bf16x8 vf10 = *(const bf16x8*)(vp1 + q16 * 64 + g * 16);
        bf16x8 vf11 = *(const bf16x8*)(vp1 + 1024 + q16 * 64 + g * 16);
        asm volatile("s_waitcnt lgkmcnt(0)" ::: "memory");
        SBAR();
        __builtin_amdgcn_s_barrier();            // buf bf free for it+2's stage

        // ---- compute: two independent r9 chains ----
        f32x4 z = {0, 0, 0, 0};
        f32x4 s00 = MFMA(kf00, qf0, z);          // b=0
        f32x4 s01 = MFMA(kf01, qf0, z);
        s00 += b00 + nn0;
        s01 += b01 + nn1;
        f32x4 s10 = MFMA(kf10, qf1, z);          // b=1
        f32x4 s11 = MFMA(kf11, qf1, z);
        s10 += b10 + nn0;
        s11 += b11 + nn1;
        chain(s00, s01, vf00, vf01, m0v, l0v, a00, a01);
        chain(s10, s11, vf10, vf11, m1v, l1v, a10, a11);
    }

    // ---- epilogue: write UNNORMALIZED partials for both b's ----
    {
        const size_t q = (size_t)(qb32 + qh * 16 + q16);
        const size_t p0 = ((size_t)split * 16 + (bpair * 2 + 0) * 4 + h) * 2048 + q;
        const size_t p1 = ((size_t)split * 16 + (bpair * 2 + 1) * 4 + h) * 2048 + q;
        if (g == 0) { Pm[p0] = m0v; Pl[p0] = l0v; Pm[p1] = m1v; Pl[p1] = l1v; }
        float* pa0 = Pacc + p0 * 32;
        float* pa1 = Pacc + p1 * 32;
        #pragma unroll
        for (int i = 0; i < 4; ++i) {
            pa0[4 * g + i]      = a00[i];
            pa0[16 + 4 * g + i] = a01[i];
            pa1[4 * g + i]      = a10[i];
            pa1[16 + 4 * g + i] = a11[i];
        }
    }
}

// ---------------------------------------------------------------------------
// Kernel 3: FUSED merge + gate + output GEMM.  Merge math = r9/r10 combine
// (proven); epilogue = r4's wa_lds + Wo MFMA + direct out write (proven).
// 512 blocks x 256 threads (4 waves = 4 heads, one 16-q tile).
// ---------------------------------------------------------------------------
__global__ __launch_bounds__(256) void combine_kernel(
    const float* __restrict__ Pm, const float* __restrict__ Pl,
    const float* __restrict__ Pacc, const float* __restrict__ gate,
    const float* __restrict__ Wo, const float* __restrict__ bo,
    float* __restrict__ out)
{
    __shared__ unsigned short wa_lds[16][136];

    const int b  = blockIdx.x >> 7;
    const int qb = (blockIdx.x & 127) * 16;
    const int h    = threadIdx.x >> 6;
    const int lane = threadIdx.x & 63;
    const int q16 = lane & 15, g = lane >> 4;
    const size_t bh = (size_t)(b * 4 + h);
    const size_t q  = (size_t)(qb + q16);

    // ---- merge 4 kv-split partials (r9/r10 verbatim math) ----
    float ms[4], ls[4];
    #pragma unroll
    for (int s = 0; s < 4; ++s) {
        size_t idx = ((size_t)s * 16 + bh) * 2048 + q;
        ms[s] = Pm[idx];
        ls[s] = Pl[idx];
    }
    float M = fmaxf(fmaxf(ms[0], ms[1]), fmaxf(ms[2], ms[3]));
    float e[4];
    float L = 0.f;
    #pragma unroll
    for (int s = 0; s < 4; ++s) { e[s] = __expf(ms[s] - M); L += ls[s] * e[s]; }

    f32x4 o0 = {0, 0, 0, 0}, o1 = {0, 0, 0, 0};
    #pragma unroll
    for (int s = 0; s < 4; ++s) {
        const float* pa = Pacc + (((size_t)s * 16 + bh) * 2048 + q) * 32;
        f32x4 a0 = *(const f32x4*)(pa + 4 * g);
        f32x4 a1 = *(const f32x4*)(pa + 16 + 4 * g);
        o0 += a0 * e[s];
        o1 += a1 * e[s];
    }
    float invL = 1.0f / L;
    const float* grow = gate + ((size_t)b * 2048 + q) * 128 + h * 32;
    f32x4 g0 = *(const f32x4*)(grow + 4 * g);
    f32x4 g1 = *(const f32x4*)(grow + 16 + 4 * g);

    // ---- stage bf16 wa tile (r4 epilogue pattern) ----
    {
        uint2 t0, t1;
        t0.x = cvt_pk(o0[0] * invL * g0[0], o0[1] * invL * g0[1]);
        t0.y = cvt_pk(o0[2] * invL * g0[2], o0[3] * invL * g0[3]);
        t1.x = cvt_pk(o1[0] * invL * g1[0], o1[1] * invL * g1[1]);
        t1.y = cvt_pk(o1[2] * invL * g1[2], o1[3] * invL * g1[3]);
        *(uint2*)&wa_lds[q16][h * 32 + 4 * g]      = t0;
        *(uint2*)&wa_lds[q16][h * 32 + 16 + 4 * g] = t1;
    }
    __syncthreads();

    // ---- out = wa @ Wo + bo; wave h computes cols [32h, 32h+32) (r4) ----
    f32x4 oo0 = {0, 0, 0, 0}, oo1 = {0, 0, 0, 0};
    #pragma unroll
    for (int kk = 0; kk < 4; ++kk) {
        bf16x8 a = *(const bf16x8*)&wa_lds[q16][kk * 32 + g * 8];
        f32x4 l0, h0, l1, h1;
        #pragma unroll
        for (int i = 0; i < 4; ++i) {
            int k0 = kk * 32 + g * 8 + i;
            int k1 = k0 + 4;
            l0[i] = Wo[(size_t)k0 * 128 + h * 32 + q16];
            h0[i] = Wo[(size_t)k1 * 128 + h * 32 + q16];
            l1[i] = Wo[(size_t)k0 * 128 + h * 32 + 16 + q16];
            h1[i] = Wo[(size_t)k1 * 128 + h * 32 + 16 + q16];
        }
        oo0 = MFMA(a, pack8(l0, h0), oo0);
        oo1 = MFMA(a, pack8(l1, h1), oo1);
    }
    float bo0 = bo[h * 32 + q16], bo1 = bo[h * 32 + 16 + q16];
    #pragma unroll
    for (int i = 0; i < 4; ++i) {
        int row = qb + 4 * g + i;
        out[((size_t)b * 2048 + row) * 128 + h * 32 + q16]      = oo0[i] + bo0;
        out[((size_t)b * 2048 + row) * 128 + h * 32 + 16 + q16] = oo1[i] + bo1;
    }
}

// ---------------------------------------------------------------------------
extern "C" void kernel_launch(void* const* d_in, const int* in_sizes, int n_in,
                              void* d_out, int out_size, void* d_ws, size_t ws_size,
                              hipStream_t stream)
{
    const float* q_data = (const float*)d_in[0];
    const float* m_data = (const float*)d_in[1];
    const float* bias   = (const float*)d_in[2];
    const float* nbias  = (const float*)d_in[3];
    const float* Wq     = (const float*)d_in[4];
    const float* Wk     = (const float*)d_in[5];
    const float* Wv     = (const float*)d_in[6];
    const float* Wg     = (const float*)d_in[7];
    const float* bg     = (const float*)d_in[8];
    const float* Wo     = (const float*)d_in[9];
    const float* bo     = (const float*)d_in[10];
    float* out = (float*)d_out;

    char* ws = (char*)d_ws;
    unsigned short* Qb = (unsigned short*)(ws);                  //  0MB, 2MB
    unsigned short* Kb = (unsigned short*)(ws + (2u << 20));     //  2MB, 2MB
    unsigned short* VT = (unsigned short*)(ws + (4u << 20));     //  4MB, 2MB
    float*          gate = (float*)(ws + (6u << 20));            //  6MB, 4MB
    float*          Pm = (float*)(ws + (12u << 20));             // 12MB, .5MB
    float*          Pl = (float*)(ws + (12u << 20) + (512u << 10)); // .5MB
    float*          Pacc = (float*)(ws + (13u << 20));           // 13MB, 16MB

    proj_kernel<<<dim3(512), dim3(256), 0, stream>>>(
        q_data, m_data, Wq, Wk, Wv, Wg, bg, Qb, Kb, VT, gate);
    attn_kernel<<<dim3(512), dim3(512), 114688, stream>>>(
        Qb, Kb, VT, bias, nbias, Pm, Pl, Pacc);
    combine_kernel<<<dim3(512), dim3(256), 0, stream>>>(
        Pm, Pl, Pacc, gate, Wo, bo, out);
}

// Round 16
// 68.077 us; speedup vs baseline: 1.4920x; 1.2024x over previous
//
#include <hip/hip_runtime.h>
#include <cstdint>
#include <cstddef>

typedef __bf16 bf16x8 __attribute__((ext_vector_type(8)));
typedef unsigned short u16x8 __attribute__((ext_vector_type(8)));
typedef float f32x4 __attribute__((ext_vector_type(4)));
typedef unsigned u32x4 __attribute__((ext_vector_type(4)));

#define MFMA(a, b, c) __builtin_amdgcn_mfma_f32_16x16x32_bf16(a, b, c, 0, 0, 0)
#define WAITV(N) asm volatile("s_waitcnt vmcnt(" #N ")" ::: "memory")
#define SBAR()   __builtin_amdgcn_sched_barrier(0)

__device__ __forceinline__ unsigned short f2bfbits(float x) {
    unsigned u = __builtin_bit_cast(unsigned, x);
    u += 0x7FFFu + ((u >> 16) & 1u);           // round-to-nearest-even
    return (unsigned short)(u >> 16);
}

// HW packed f32->bf16 (RNE)
__device__ __forceinline__ unsigned cvt_pk(float lo, float hi) {
    unsigned r;
    asm("v_cvt_pk_bf16_f32 %0, %1, %2" : "=v"(r) : "v"(lo), "v"(hi));
    return r;
}

__device__ __forceinline__ bf16x8 pack8(f32x4 a, f32x4 b) {
    u32x4 t = { cvt_pk(a[0], a[1]), cvt_pk(a[2], a[3]),
                cvt_pk(b[0], b[1]), cvt_pk(b[2], b[3]) };
    return __builtin_bit_cast(bf16x8, t);
}

// async global->LDS DMA, 16B/lane; LDS dest = wave-uniform base + lane*16.
__device__ __forceinline__ void gl_lds16(const void* g, void* l) {
    __builtin_amdgcn_global_load_lds(
        (const __attribute__((address_space(1))) unsigned int*)g,
        (__attribute__((address_space(3))) unsigned int*)l, 16, 0, 0);
}

// ---------------------------------------------------------------------------
// Kernel 1: projections (r10/r15 verbatim; proven rounds 1-15).
// ---------------------------------------------------------------------------
__global__ __launch_bounds__(256) void proj_kernel(
    const float* __restrict__ q_data, const float* __restrict__ m_data,
    const float* __restrict__ Wq, const float* __restrict__ Wk,
    const float* __restrict__ Wv, const float* __restrict__ Wg,
    const float* __restrict__ bg,
    unsigned short* __restrict__ Qb, unsigned short* __restrict__ Kb,
    unsigned short* __restrict__ VT, float* __restrict__ gate)
{
    __shared__ unsigned short vt_lds[128][80];
    const int mat   = blockIdx.x >> 7;
    const int mtile = blockIdx.x & 127;
    const int wave  = threadIdx.x >> 6;
    const int lane  = threadIdx.x & 63;
    const int r16 = lane & 15, g = lane >> 4;
    const int rowbase = mtile * 64 + wave * 16;

    const float* src = (mat == 1 || mat == 2) ? m_data : q_data;
    const float* W   = (mat == 0) ? Wq : (mat == 1) ? Wk : (mat == 2) ? Wv : Wg;

    bf16x8 afrag[4];
    {
        const float* arow = src + (size_t)(rowbase + r16) * 128;
        #pragma unroll
        for (int kk = 0; kk < 4; ++kk) {
            f32x4 lo = *(const f32x4*)(arow + kk * 32 + g * 8);
            f32x4 hi = *(const f32x4*)(arow + kk * 32 + g * 8 + 4);
            afrag[kk] = pack8(lo, hi);
        }
    }

    f32x4 acc[8];
    #pragma unroll
    for (int n0 = 0; n0 < 8; ++n0) {
        f32x4 a = {0.f, 0.f, 0.f, 0.f};
        #pragma unroll
        for (int kk = 0; kk < 4; ++kk) {
            f32x4 lo, hi;
            #pragma unroll
            for (int i = 0; i < 4; ++i) {
                lo[i] = W[(size_t)(kk * 32 + g * 8 + i) * 128 + n0 * 16 + r16];
                hi[i] = W[(size_t)(kk * 32 + g * 8 + 4 + i) * 128 + n0 * 16 + r16];
            }
            a = MFMA(afrag[kk], pack8(lo, hi), a);
        }
        acc[n0] = a;
    }

    if (mat <= 1) {
        unsigned short* dst = (mat == 0) ? Qb : Kb;
        #pragma unroll
        for (int n0 = 0; n0 < 8; ++n0) {
            int n = n0 * 16 + r16, h = n >> 5, d = n & 31;
            #pragma unroll
            for (int i = 0; i < 4; ++i) {
                int grow = rowbase + 4 * g + i;
                int bb = grow >> 11, ns = grow & 2047;
                dst[(size_t)(bb * 4 + h) * 65536 + (size_t)ns * 32 + d] =
                    f2bfbits(acc[n0][i]);
            }
        }
    } else if (mat == 2) {
        #pragma unroll
        for (int n0 = 0; n0 < 8; ++n0) {
            int n = n0 * 16 + r16;
            #pragma unroll
            for (int i = 0; i < 4; ++i)
                vt_lds[n][wave * 16 + 4 * g + i] = f2bfbits(acc[n0][i]);
        }
        __syncthreads();
        int bb = rowbase >> 11;
        int nsbase = (mtile * 64) & 2047;
        #pragma unroll
        for (int it = 0; it < 4; ++it) {
            int idx = (threadIdx.x + it * 256) * 8;
            int n = idx >> 6, mm = idx & 63;
            u16x8 v = *(const u16x8*)&vt_lds[n][mm];
            *(u16x8*)(VT + (size_t)(bb * 128 + n) * 2048 + nsbase + mm) = v;
        }
    } else {
        #pragma unroll
        for (int n0 = 0; n0 < 8; ++n0) {
            int n = n0 * 16 + r16;
            float bgv = bg[n];
            #pragma unroll
            for (int i = 0; i < 4; ++i) {
                int grow = rowbase + 4 * g + i;
                float x = acc[n0][i] + bgv;
                gate[(size_t)grow * 128 + n] = 1.0f / (1.0f + __expf(-x));
            }
        }
    }
}

// ---------------------------------------------------------------------------
// Kernel 2: flash attention partials.  Index-only re-parameterization of the
// r10/r15-PROVEN kernel (the one structural-edit class that has passed):
// QB 32->64, waves 8->16 (block = 1024 thr; wave = (q-quarter qh in [0,4),
// head h)).  Each wave keeps r10's EXACT 2-chain structure, chunk shapes
// (1KB DMA, 16B/lane), swizzle formulas ((lc8*4)^(ls8<<2) write / (q16&7)<<4
// read), sigma K-permutation, ring-2 it&1 slots, counted-vmcnt + 2 barriers.
// Changes are ONLY: block decomposition (grid 256 = 4 splits x 2 bpairs x
// 32 qt64), wave->chunk assignment (each wave: 1 bias + 2 nbias + 1 K + 1 V
// = uniform 5 DMAs -> WAITV(5)), slot 80KB, ring-2 = 160KB dynamic LDS.
// Staged bytes 448->320MB (K/V q-amp halved); in-flight 56->80KB/CU.
// ---------------------------------------------------------------------------
#define NB_OFF 16384
#define K_OFF  49152
#define V_OFF  65536
#define SLOT_SZ 81920

__global__ __launch_bounds__(1024, 1) void attn_kernel(
    const unsigned short* __restrict__ Qb, const unsigned short* __restrict__ Kb,
    const unsigned short* __restrict__ VT,
    const float* __restrict__ bias, const float* __restrict__ nbias,
    float* __restrict__ Pm, float* __restrict__ Pl, float* __restrict__ Pacc)
{
    extern __shared__ __align__(16) char pool[];   // 160KB, ring-2 x 80KB

    const int split = blockIdx.x >> 6;             // [0,4)
    const int rem   = blockIdx.x & 63;
    const int bpair = rem >> 5;                    // [0,2)
    const int qt    = rem & 31;                    // [0,32)
    const int qb64  = qt * 64;
    const int kv0   = split * 512;

    const int w    = threadIdx.x >> 6;             // [0,16)
    const int h    = w & 3;
    const int qh   = w >> 2;                       // q-quarter [0,4)
    const int lane = threadIdx.x & 63;
    const int q16 = lane & 15, g = lane >> 4;

    // staging lane decompositions (r10 verbatim)
    const int ls8 = lane >> 3, lc8 = lane & 7;        // bias/nbias chunks
    const int rho = lane >> 2, l4 = lane & 3;         // K/V chunks
    const int krow_l = ((rho >> 2) << 3) + (rho & 3); // sigma permutation

    const int b0 = bpair * 2, b1 = b0 + 1;
    const int bsl = qh & 1;                        // b this wave stages K/V for
    const int tsl = qh >> 1;                       // chunk index t / j

    // global bases
    const float* bias_w = bias
        + ((size_t)((b0 + (w >> 3)) * 2048 + qb64 + (w & 7) * 8)) * 2048;
    const float* nb_w = nbias + ((size_t)(h * 2048 + qb64 + qh * 16)) * 2048;
    const unsigned short* Kp_w = Kb + (size_t)((b0 + bsl) * 4 + h) * 65536;
    const unsigned short* Vp_w = VT + (size_t)((b0 + bsl) * 4 + h) * 65536;

    // Q fragments for both local b's (plain loads; retired by first WAITV)
    bf16x8 qf0 = *(const bf16x8*)(Qb + (size_t)(b0 * 4 + h) * 65536
                                  + (size_t)(qb64 + qh * 16 + q16) * 32 + g * 8);
    bf16x8 qf1 = *(const bf16x8*)(Qb + (size_t)(b1 * 4 + h) * 65536
                                  + (size_t)(qb64 + qh * 16 + q16) * 32 + g * 8);

    float m0v = -1e30f, l0v = 0.f, m1v = -1e30f, l1v = 0.f;
    f32x4 a00 = {0, 0, 0, 0}, a01 = {0, 0, 0, 0};   // b=0: d 0-15, 16-31
    f32x4 a10 = {0, 0, 0, 0}, a11 = {0, 0, 0, 0};   // b=1

    // ---- stage tile it -> ring slot it&1; UNIFORM 5 DMAs on every wave ----
    auto stage = [&](int it) {
        if (it >= 16) return;
        const int bf = it & 1;
        const int kb = kv0 + it * 32;
        char* base = pool + bf * SLOT_SZ;
        const int csw0 = (lc8 * 4) ^ (ls8 << 2);      // r10 chunk swizzle (f32)
        // bias: b = w>>3, rows (w&7)*8 + ls8 of the 64-row tile       [1 DMA]
        gl_lds16(bias_w + (size_t)ls8 * 2048 + kb + csw0,
                 base + (w >> 3) * 8192 + (w & 7) * 1024);
        // nbias: own h, rows qh*16 + 8c + ls8                         [2 DMA]
        #pragma unroll
        for (int c = 0; c < 2; ++c)
            gl_lds16(nb_w + (size_t)(8 * c + ls8) * 2048 + kb + csw0,
                     base + NB_OFF + h * 8192 + qh * 2048 + c * 1024);
        // K: (b=bsl, h), chunk t=tsl, sigma-permuted (r10 verbatim)   [1 DMA]
        gl_lds16(Kp_w + (size_t)(kb + 4 * tsl + krow_l) * 32 + l4 * 8,
                 base + K_OFF + bsl * 8192 + h * 2048 + tsl * 1024);
        // V: (b=bsl, h), chunk j=tsl (r10 verbatim)                   [1 DMA]
        gl_lds16(Vp_w + (size_t)(16 * tsl + rho) * 2048 + kb + l4 * 8,
                 base + V_OFF + bsl * 8192 + h * 2048 + tsl * 1024);
    };

    // ---- softmax+PV chain (r9/r10 verbatim) ----
    auto chain = [&](f32x4 s0, f32x4 s1, bf16x8 vf0, bf16x8 vf1,
                     float& m, float& lsum, f32x4& ac0, f32x4& ac1) {
        float mx = fmaxf(fmaxf(fmaxf(s0[0], s0[1]), fmaxf(s0[2], s0[3])),
                         fmaxf(fmaxf(s1[0], s1[1]), fmaxf(s1[2], s1[3])));
        mx = fmaxf(mx, __shfl_xor(mx, 16));
        mx = fmaxf(mx, __shfl_xor(mx, 32));
        float m_new = fmaxf(m, mx);
        float alpha = __expf(m - m_new);
        float ps = 0.f;
        #pragma unroll
        for (int i = 0; i < 4; ++i) { s0[i] = __expf(s0[i] - m_new); ps += s0[i]; }
        #pragma unroll
        for (int i = 0; i < 4; ++i) { s1[i] = __expf(s1[i] - m_new); ps += s1[i]; }
        ps += __shfl_xor(ps, 16);
        ps += __shfl_xor(ps, 32);
        lsum = lsum * alpha + ps;
        m = m_new;
        u32x4 pc = { cvt_pk(s0[0], s0[1]), cvt_pk(s0[2], s0[3]),
                     cvt_pk(s1[0], s1[1]), cvt_pk(s1[2], s1[3]) };
        bf16x8 p = __builtin_bit_cast(bf16x8, pc);
        ac0 *= alpha;
        ac1 *= alpha;
        ac0 = MFMA(vf0, p, ac0);
        ac1 = MFMA(vf1, p, ac1);
    };

    stage(0);

    #pragma unroll 2
    for (int it = 0; it < 16; ++it) {
        const int bf = it & 1;
        if (it < 15) {
            stage(it + 1);
            WAITV(5);                            // stage(it) retired
        } else {
            WAITV(0);
        }
        SBAR();
        __builtin_amdgcn_s_barrier();            // tile it visible to all waves

        // ---- LDS -> regs (r10 verbatim read formulas; row = qh*16+q16) ----
        const char* slot = pool + bf * SLOT_SZ;
        const int r128 = (qh * 16 + q16) * 128;
        const int rsw  = (q16 & 7) << 4;
        const char* np = slot + NB_OFF + h * 8192;
        f32x4 nn0 = *(const f32x4*)(np + r128 + ((g * 32) ^ rsw));
        f32x4 nn1 = *(const f32x4*)(np + r128 + ((16 + g * 32) ^ rsw));
        const char* bp0 = slot;                  // bias b=0 region
        f32x4 b00 = *(const f32x4*)(bp0 + r128 + ((g * 32) ^ rsw));
        f32x4 b01 = *(const f32x4*)(bp0 + r128 + ((16 + g * 32) ^ rsw));
        const char* bp1 = bp0 + 8192;            // bias b=1 region
        f32x4 b10 = *(const f32x4*)(bp1 + r128 + ((g * 32) ^ rsw));
        f32x4 b11 = *(const f32x4*)(bp1 + r128 + ((16 + g * 32) ^ rsw));
        const char* kp0 = slot + K_OFF + h * 2048;
        bf16x8 kf00 = *(const bf16x8*)(kp0 + q16 * 64 + g * 16);
        bf16x8 kf01 = *(const bf16x8*)(kp0 + 1024 + q16 * 64 + g * 16);
        const char* kp1 = kp0 + 8192;
        bf16x8 kf10 = *(const bf16x8*)(kp1 + q16 * 64 + g * 16);
        bf16x8 kf11 = *(const bf16x8*)(kp1 + 1024 + q16 * 64 + g * 16);
        const char* vp0 = slot + V_OFF + h * 2048;
        bf16x8 vf00 = *(const bf16x8*)(vp0 + q16 * 64 + g * 16);
        bf16x8 vf01 = *(const bf16x8*)(vp0 + 1024 + q16 * 64 + g * 16);
        const char* vp1 = vp0 + 8192;
        bf16x8 vf10 = *(const bf16x8*)(vp1 + q16 * 64 + g * 16);
        bf16x8 vf11 = *(const bf16x8*)(vp1 + 1024 + q16 * 64 + g * 16);
        asm volatile("s_waitcnt lgkmcnt(0)" ::: "memory");
        SBAR();
        __builtin_amdgcn_s_barrier();            // buf bf free for it+2's stage

        // ---- compute: two independent r10 chains ----
        f32x4 z = {0, 0, 0, 0};
        f32x4 s00 = MFMA(kf00, qf0, z);          // b=0
        f32x4 s01 = MFMA(kf01, qf0, z);
        s00 += b00 + nn0;
        s01 += b01 + nn1;
        f32x4 s10 = MFMA(kf10, qf1, z);          // b=1
        f32x4 s11 = MFMA(kf11, qf1, z);
        s10 += b10 + nn0;
        s11 += b11 + nn1;
        chain(s00, s01, vf00, vf01, m0v, l0v, a00, a01);
        chain(s10, s11, vf10, vf11, m1v, l1v, a10, a11);
    }

    // ---- epilogue: write UNNORMALIZED partials for both b's (r10) ----
    {
        const size_t q = (size_t)(qb64 + qh * 16 + q16);
        const size_t p0 = ((size_t)split * 16 + (b0 * 4 + h)) * 2048 + q;
        const size_t p1 = ((size_t)split * 16 + (b1 * 4 + h)) * 2048 + q;
        if (g == 0) { Pm[p0] = m0v; Pl[p0] = l0v; Pm[p1] = m1v; Pl[p1] = l1v; }
        float* pa0 = Pacc + p0 * 32;
        float* pa1 = Pacc + p1 * 32;
        #pragma unroll
        for (int i = 0; i < 4; ++i) {
            pa0[4 * g + i]      = a00[i];
            pa0[16 + 4 * g + i] = a01[i];
            pa1[4 * g + i]      = a10[i];
            pa1[16 + 4 * g + i] = a11[i];
        }
    }
}

// ---------------------------------------------------------------------------
// Kernel 3: FUSED merge + gate + output GEMM (r15 verbatim, proven).
// ---------------------------------------------------------------------------
__global__ __launch_bounds__(256) void combine_kernel(
    const float* __restrict__ Pm, const float* __restrict__ Pl,
    const float* __restrict__ Pacc, const float* __restrict__ gate,
    const float* __restrict__ Wo, const float* __restrict__ bo,
    float* __restrict__ out)
{
    __shared__ unsigned short wa_lds[16][136];

    const int b  = blockIdx.x >> 7;
    const int qb = (blockIdx.x & 127) * 16;
    const int h    = threadIdx.x >> 6;
    const int lane = threadIdx.x & 63;
    const int q16 = lane & 15, g = lane >> 4;
    const size_t bh = (size_t)(b * 4 + h);
    const size_t q  = (size_t)(qb + q16);

    float ms[4], ls[4];
    #pragma unroll
    for (int s = 0; s < 4; ++s) {
        size_t idx = ((size_t)s * 16 + bh) * 2048 + q;
        ms[s] = Pm[idx];
        ls[s] = Pl[idx];
    }
    float M = fmaxf(fmaxf(ms[0], ms[1]), fmaxf(ms[2], ms[3]));
    float e[4];
    float L = 0.f;
    #pragma unroll
    for (int s = 0; s < 4; ++s) { e[s] = __expf(ms[s] - M); L += ls[s] * e[s]; }

    f32x4 o0 = {0, 0, 0, 0}, o1 = {0, 0, 0, 0};
    #pragma unroll
    for (int s = 0; s < 4; ++s) {
        const float* pa = Pacc + (((size_t)s * 16 + bh) * 2048 + q) * 32;
        f32x4 a0 = *(const f32x4*)(pa + 4 * g);
        f32x4 a1 = *(const f32x4*)(pa + 16 + 4 * g);
        o0 += a0 * e[s];
        o1 += a1 * e[s];
    }
    float invL = 1.0f / L;
    const float* grow = gate + ((size_t)b * 2048 + q) * 128 + h * 32;
    f32x4 g0 = *(const f32x4*)(grow + 4 * g);
    f32x4 g1 = *(const f32x4*)(grow + 16 + 4 * g);

    {
        uint2 t0, t1;
        t0.x = cvt_pk(o0[0] * invL * g0[0], o0[1] * invL * g0[1]);
        t0.y = cvt_pk(o0[2] * invL * g0[2], o0[3] * invL * g0[3]);
        t1.x = cvt_pk(o1[0] * invL * g1[0], o1[1] * invL * g1[1]);
        t1.y = cvt_pk(o1[2] * invL * g1[2], o1[3] * invL * g1[3]);
        *(uint2*)&wa_lds[q16][h * 32 + 4 * g]      = t0;
        *(uint2*)&wa_lds[q16][h * 32 + 16 + 4 * g] = t1;
    }
    __syncthreads();

    f32x4 oo0 = {0, 0, 0, 0}, oo1 = {0, 0, 0, 0};
    #pragma unroll
    for (int kk = 0; kk < 4; ++kk) {
        bf16x8 a = *(const bf16x8*)&wa_lds[q16][kk * 32 + g * 8];
        f32x4 l0, h0, l1, h1;
        #pragma unroll
        for (int i = 0; i < 4; ++i) {
            int k0 = kk * 32 + g * 8 + i;
            int k1 = k0 + 4;
            l0[i] = Wo[(size_t)k0 * 128 + h * 32 + q16];
            h0[i] = Wo[(size_t)k1 * 128 + h * 32 + q16];
            l1[i] = Wo[(size_t)k0 * 128 + h * 32 + 16 + q16];
            h1[i] = Wo[(size_t)k1 * 128 + h * 32 + 16 + q16];
        }
        oo0 = MFMA(a, pack8(l0, h0), oo0);
        oo1 = MFMA(a, pack8(l1, h1), oo1);
    }
    float bo0 = bo[h * 32 + q16], bo1 = bo[h * 32 + 16 + q16];
    #pragma unroll
    for (int i = 0; i < 4; ++i) {
        int row = qb + 4 * g + i;
        out[((size_t)b * 2048 + row) * 128 + h * 32 + q16]      = oo0[i] + bo0;
        out[((size_t)b * 2048 + row) * 128 + h * 32 + 16 + q16] = oo1[i] + bo1;
    }
}

// ---------------------------------------------------------------------------
extern "C" void kernel_launch(void* const* d_in, const int* in_sizes, int n_in,
                              void* d_out, int out_size, void* d_ws, size_t ws_size,
                              hipStream_t stream)
{
    const float* q_data = (const float*)d_in[0];
    const float* m_data = (const float*)d_in[1];
    const float* bias   = (const float*)d_in[2];
    const float* nbias  = (const float*)d_in[3];
    const float* Wq     = (const float*)d_in[4];
    const float* Wk     = (const float*)d_in[5];
    const float* Wv     = (const float*)d_in[6];
    const float* Wg     = (const float*)d_in[7];
    const float* bg     = (const float*)d_in[8];
    const float* Wo     = (const float*)d_in[9];
    const float* bo     = (const float*)d_in[10];
    float* out = (float*)d_out;

    char* ws = (char*)d_ws;
    unsigned short* Qb = (unsigned short*)(ws);                  //  0MB, 2MB
    unsigned short* Kb = (unsigned short*)(ws + (2u << 20));     //  2MB, 2MB
    unsigned short* VT = (unsigned short*)(ws + (4u << 20));     //  4MB, 2MB
    float*          gate = (float*)(ws + (6u << 20));            //  6MB, 4MB
    float*          Pm = (float*)(ws + (12u << 20));             // 12MB, .5MB
    float*          Pl = (float*)(ws + (12u << 20) + (512u << 10)); // .5MB
    float*          Pacc = (float*)(ws + (13u << 20));           // 13MB, 16MB

    proj_kernel<<<dim3(512), dim3(256), 0, stream>>>(
        q_data, m_data, Wq, Wk, Wv, Wg, bg, Qb, Kb, VT, gate);
    attn_kernel<<<dim3(256), dim3(1024), 163840, stream>>>(
        Qb, Kb, VT, bias, nbias, Pm, Pl, Pacc);
    combine_kernel<<<dim3(512), dim3(256), 0, stream>>>(
        Pm, Pl, Pacc, gate, Wo, bo, out);
}